// Round 1
// 3192.906 us; speedup vs baseline: 1.0602x; 1.0602x over previous
//
#include <hip/hip_runtime.h>
#include <math.h>

#define LRELU(v) ((v) > 0.f ? (v) : 0.01f * (v))

typedef __attribute__((ext_vector_type(8))) short bf8v;   // 8 x bf16 (4 VGPRs)
typedef __attribute__((ext_vector_type(4))) float f4v;    // MFMA accumulator

// fp32 -> bf16 round-to-nearest-even
static __device__ __forceinline__ unsigned short f2b(float f) {
    unsigned int u = __float_as_uint(f);
    unsigned int r = (u + 0x7fffu + ((u >> 16) & 1u)) >> 16;
    return (unsigned short)r;
}

// async global->LDS, 16B per lane. HW semantics: wave-uniform base + lane*16,
// so per-thread dest MUST be base + tid*16 (linear). [guide §5]
static __device__ __forceinline__ void gload16(const unsigned short* g, unsigned short* l) {
    __builtin_amdgcn_global_load_lds(
        (__attribute__((address_space(1))) void*)(g),
        (__attribute__((address_space(3))) void*)(l), 16, 0, 0);
}

// ---------------------------------------------------------------------------
// K1: build full-res image, pixel-major bf16 [36864][10]
// ---------------------------------------------------------------------------
__global__ __launch_bounds__(256) void k_build_full(const float* __restrict__ in,
                                                    unsigned short* __restrict__ full0) {
    int idx = blockIdx.x * 256 + threadIdx.x;
    if (idx >= 368640) return;
    int c = idx % 10, pix = idx / 10;
    int X = pix % 192, Y = pix / 192;
    int t = (Y & 3) * 4 + (X & 3);
    int h = Y >> 2, w = X >> 2;
    full0[idx] = f2b(in[(((t * 10 + c) * 48) + h) * 48 + w]);
}

// ---------------------------------------------------------------------------
// K2: weight convert+permute fp32 -> bf16.  src (Mv, C, Q) row-major,
// dst [gridDim.x(Mp)][Kp] with kp = q*C + c; zero pad (m>=Mv or kp>=C*Q).
// ---------------------------------------------------------------------------
template <int C, int Q>
__global__ __launch_bounds__(256) void k_wcvt(const float* __restrict__ src,
                                              unsigned short* __restrict__ dst,
                                              int Mv, int Kp) {
    int m = blockIdx.x;
    for (int kp = threadIdx.x; kp < Kp; kp += 256) {
        float v = 0.f;
        if (m < Mv && kp < C * Q) {
            int qq = kp / C, c = kp - qq * C;
            v = src[((size_t)m * C + c) * Q + qq];
        }
        dst[(size_t)m * Kp + kp] = f2b(v);
    }
}

// K2b: flat fp32 -> bf16 convert (identity layout, for 1x1-conv weights)
__global__ __launch_bounds__(256) void k_cvt_flat(const float* __restrict__ src,
                                                  unsigned short* __restrict__ dst,
                                                  size_t n) {
    size_t i = ((size_t)blockIdx.x * 256 + threadIdx.x) * 4;
    if (i >= n) return;
    float4 v = *(const float4*)(src + i);
    ushort4 o;
    o.x = f2b(v.x); o.y = f2b(v.y); o.z = f2b(v.z); o.w = f2b(v.w);
    *(ushort4*)(dst + i) = o;
}

// ---------------------------------------------------------------------------
// K3: im2col 3x3 pad1, pixel-major bf16 src [H*W][C] -> dst [H*W][Kp]
// ---------------------------------------------------------------------------
template <int C>
__global__ __launch_bounds__(256) void k_im2col3(const unsigned short* __restrict__ src,
                                                 unsigned short* __restrict__ dst,
                                                 int W, int H, int Kp) {
    int p = blockIdx.x;
    int x = p % W, y = p / W;
    for (int kp = threadIdx.x; kp < Kp; kp += 256) {
        unsigned short v = 0;
        if (kp < 9 * C) {
            int qq = kp / C, c = kp - qq * C;
            int yy = y + qq / 3 - 1, xx = x + qq % 3 - 1;
            if (yy >= 0 && yy < H && xx >= 0 && xx < W)
                v = src[(size_t)(yy * W + xx) * C + c];
        }
        dst[(size_t)p * Kp + kp] = v;
    }
}

// ---------------------------------------------------------------------------
// K4: im2col 4x4 stride4: src [36864][100] -> dst [2304][1600]
// ---------------------------------------------------------------------------
__global__ __launch_bounds__(256) void k_im2col4(const unsigned short* __restrict__ src,
                                                 unsigned short* __restrict__ dst) {
    int p = blockIdx.x;  // 0..2303
    int x = p % 48, y = p / 48;
    for (int kp = threadIdx.x; kp < 1600; kp += 256) {
        int qq = kp / 100, c = kp - qq * 100;
        int yy = y * 4 + (qq >> 2), xx = x * 4 + (qq & 3);
        dst[(size_t)p * 1600 + kp] = src[(size_t)(yy * 192 + xx) * 100 + c];
    }
}

// ---------------------------------------------------------------------------
// K5: MFMA GEMM, m97 structure: linear LDS [128][32], global_load_lds staging.
// D[m][n] = act(A[m][k]*Bt[n][k] + bias[m]) stored TRANSPOSED out[n][m].
// A bf16 [>=ceil128(M)][K] (rows padded w/ zeros), Bt bf16 [N][K], K%32==0,
// N multiple of 128.  Block 256 thr = 4 waves, tile 128x128, wave 64x64.
// mfma_f32_16x16x32_bf16:  A-frag lane l: A[m=l&15][k=(l>>4)*8+j]
//                          B-frag lane l: B[k=(l>>4)*8+j][n=l&15]
//                          D lane l reg r: D[row=(l>>4)*4+r][col=l&15]
// ---------------------------------------------------------------------------
template <int ACT, int OF32>
__global__ __launch_bounds__(256) void k_gemm(
    const unsigned short* __restrict__ A, const unsigned short* __restrict__ Bt,
    const float* __restrict__ bias, void* __restrict__ outv,
    int K, int Mv, int ldout) {
    __shared__ __align__(16) unsigned short As[128 * 32];
    __shared__ __align__(16) unsigned short Bs[128 * 32];
    const int tid = threadIdx.x;
    const int lane = tid & 63;
    const int w = tid >> 6;
    const int wm = w >> 1, wn = w & 1;
    const int q = lane >> 4, ln = lane & 15;
    const int m0 = blockIdx.y * 128, n0 = blockIdx.x * 128;

    f4v acc[4][4];
#pragma unroll
    for (int i = 0; i < 4; ++i)
#pragma unroll
        for (int j = 0; j < 4; ++j) acc[i][j] = (f4v){0.f, 0.f, 0.f, 0.f};

    // staging chunk: thread tid -> row tid>>2, k8 = (tid&3)*8; lds byte = tid*16
    const int br0 = tid >> 2, bk0 = (tid & 3) << 3;
    const unsigned short* pA0 = A + (size_t)(m0 + br0) * K + bk0;
    const unsigned short* pA1 = pA0 + (size_t)64 * K;
    const unsigned short* pB0 = Bt + (size_t)(n0 + br0) * K + bk0;
    const unsigned short* pB1 = pB0 + (size_t)64 * K;
    unsigned short* lA0 = As + tid * 8;         // tid*16 bytes (linear)
    unsigned short* lA1 = As + 2048 + tid * 8;  // rows 64..127
    unsigned short* lB0 = Bs + tid * 8;
    unsigned short* lB1 = Bs + 2048 + tid * 8;
    const unsigned short* Ap2 = &As[(wm * 64 + ln) * 32 + q * 8];
    const unsigned short* Bp2 = &Bs[(wn * 64 + ln) * 32 + q * 8];

    for (int k0 = 0; k0 < K; k0 += 32) {
        gload16(pA0 + k0, lA0);
        gload16(pA1 + k0, lA1);
        gload16(pB0 + k0, lB0);
        gload16(pB1 + k0, lB1);
        __syncthreads();  // compiler drains vmcnt(0) before barrier
        bf8v af[4], bfv[4];
#pragma unroll
        for (int i = 0; i < 4; ++i) af[i] = *(const bf8v*)(Ap2 + i * 512);
#pragma unroll
        for (int j = 0; j < 4; ++j) bfv[j] = *(const bf8v*)(Bp2 + j * 512);
#pragma unroll
        for (int i = 0; i < 4; ++i)
#pragma unroll
            for (int j = 0; j < 4; ++j)
                acc[i][j] = __builtin_amdgcn_mfma_f32_16x16x32_bf16(af[i], bfv[j], acc[i][j], 0, 0, 0);
        __syncthreads();
    }

    // transposed epilogue: per-wave 16x17 LDS tile (intra-wave only)
    float* tb = ((float*)As) + w * 288;
#pragma unroll
    for (int i = 0; i < 4; ++i) {
        const int mbase = m0 + wm * 64 + i * 16;
        float bi[4];
#pragma unroll
        for (int r = 0; r < 4; ++r) {
            int mm = mbase + q * 4 + r;
            bi[r] = (mm < Mv) ? bias[mm] : 0.f;
        }
#pragma unroll
        for (int j = 0; j < 4; ++j) {
            const int nbase = n0 + wn * 64 + j * 16;
#pragma unroll
            for (int r = 0; r < 4; ++r) {
                float v = acc[i][j][r] + bi[r];
                v = ACT ? tanhf(v) : LRELU(v);
                tb[ln * 17 + q * 4 + r] = v;  // tb[col][row] = D[row][col]
            }
#pragma unroll
            for (int r = 0; r < 4; ++r) {
                float v = tb[(q * 4 + r) * 17 + ln];  // = D[row=ln][col=q*4+r]
                size_t n = nbase + q * 4 + r;
                int m = mbase + ln;
                if (m < Mv) {
                    if (OF32) ((float*)outv)[n * (size_t)ldout + m] = v;
                    else ((unsigned short*)outv)[n * (size_t)ldout + m] = f2b(v);
                }
            }
        }
    }
}

// ---------------------------------------------------------------------------
// K5b: legacy reg-staged GEMM with in-loop fp32->bf16 A conversion (fallback
// for ww2 when workspace is too small to pre-convert). Verified round-0 code.
// ---------------------------------------------------------------------------
template <int ACT, int OF32, int AF32>
__global__ __launch_bounds__(256) void k_gemm_f32a(
    const void* __restrict__ Ain, const unsigned short* __restrict__ Bt,
    const float* __restrict__ bias, void* __restrict__ outv,
    int K, int Mv, int ldout) {
    __shared__ __align__(16) unsigned short As[128 * 40];
    __shared__ __align__(16) unsigned short Bs[128 * 40];
    const int tid = threadIdx.x;
    const int lane = tid & 63;
    const int w = tid >> 6;
    const int wm = w >> 1, wn = w & 1;
    const int q = lane >> 4, ln = lane & 15;
    const int m0 = blockIdx.y * 128, n0 = blockIdx.x * 128;

    f4v acc[4][4];
#pragma unroll
    for (int i = 0; i < 4; ++i)
#pragma unroll
        for (int j = 0; j < 4; ++j) acc[i][j] = (f4v){0.f, 0.f, 0.f, 0.f};

    const int br0 = tid >> 2, bk0 = (tid & 3) << 3;
    const int br1 = br0 + 64;
    const int bl0 = br0 * 40 + bk0, bl1 = br1 * 40 + bk0;
    const unsigned short* pB0 = Bt + (size_t)(n0 + br0) * K + bk0;
    const unsigned short* pB1 = Bt + (size_t)(n0 + br1) * K + bk0;

    const unsigned short* Ab = (const unsigned short*)Ain;
    const float* Af = (const float*)Ain;
    const unsigned short* pA0 = Ab + (size_t)(m0 + br0) * K + bk0;
    const unsigned short* pA1 = Ab + (size_t)(m0 + br1) * K + bk0;
    const int fr = tid >> 3, fk = (tid & 7) << 2;
    const float* pF = Af + (size_t)(m0 + fr) * K + fk;

    for (int k0 = 0; k0 < K; k0 += 32) {
        if (AF32) {
#pragma unroll
            for (int jj = 0; jj < 4; ++jj) {
                float4 v = *(const float4*)(pF + (size_t)jj * 32 * K + k0);
                unsigned int lo = ((unsigned)f2b(v.y) << 16) | f2b(v.x);
                unsigned int hi = ((unsigned)f2b(v.w) << 16) | f2b(v.z);
                *(uint2*)&As[(fr + jj * 32) * 40 + fk] = make_uint2(lo, hi);
            }
        } else {
            uint4 a0 = *(const uint4*)(pA0 + k0);
            uint4 a1 = *(const uint4*)(pA1 + k0);
            *(uint4*)&As[bl0] = a0;
            *(uint4*)&As[bl1] = a1;
        }
        uint4 b0 = *(const uint4*)(pB0 + k0);
        uint4 b1 = *(const uint4*)(pB1 + k0);
        *(uint4*)&Bs[bl0] = b0;
        *(uint4*)&Bs[bl1] = b1;
        __syncthreads();
        const unsigned short* Ap2 = &As[(wm * 64 + ln) * 40 + q * 8];
        const unsigned short* Bp2 = &Bs[(wn * 64 + ln) * 40 + q * 8];
        bf8v af[4], bfv[4];
#pragma unroll
        for (int i = 0; i < 4; ++i) af[i] = *(const bf8v*)(Ap2 + i * 640);
#pragma unroll
        for (int j = 0; j < 4; ++j) bfv[j] = *(const bf8v*)(Bp2 + j * 640);
#pragma unroll
        for (int i = 0; i < 4; ++i)
#pragma unroll
            for (int j = 0; j < 4; ++j)
                acc[i][j] = __builtin_amdgcn_mfma_f32_16x16x32_bf16(af[i], bfv[j], acc[i][j], 0, 0, 0);
        __syncthreads();
    }

    float* tb = ((float*)As) + w * 288;
#pragma unroll
    for (int i = 0; i < 4; ++i) {
        const int mbase = m0 + wm * 64 + i * 16;
        float bi[4];
#pragma unroll
        for (int r = 0; r < 4; ++r) {
            int mm = mbase + q * 4 + r;
            bi[r] = (mm < Mv) ? bias[mm] : 0.f;
        }
#pragma unroll
        for (int j = 0; j < 4; ++j) {
            const int nbase = n0 + wn * 64 + j * 16;
#pragma unroll
            for (int r = 0; r < 4; ++r) {
                float v = acc[i][j][r] + bi[r];
                v = ACT ? tanhf(v) : LRELU(v);
                tb[ln * 17 + q * 4 + r] = v;
            }
#pragma unroll
            for (int r = 0; r < 4; ++r) {
                float v = tb[(q * 4 + r) * 17 + ln];
                size_t n = nbase + q * 4 + r;
                int m = mbase + ln;
                if (m < Mv) {
                    if (OF32) ((float*)outv)[n * (size_t)ldout + m] = v;
                    else ((unsigned short*)outv)[n * (size_t)ldout + m] = f2b(v);
                }
            }
        }
    }
}

// ---------------------------------------------------------------------------
// K6: per-pixel normal equations + solve (verified, unchanged)
// ---------------------------------------------------------------------------
__global__ __launch_bounds__(256) void k_solve(const float* __restrict__ WmT,
                                               const float* __restrict__ design,
                                               const float* __restrict__ input,
                                               float* __restrict__ out) {
    const int p = blockIdx.x;  // 0..2303
    const int h = p / 48, wpx = p % 48;
    const int tid = threadIdx.x;
    __shared__ float Msh[16 * 17];
    __shared__ float Gsh[16 * 17];
    __shared__ float Xsh[16 * 8];
    __shared__ float Ysh[16 * 4];
    __shared__ float XTWsh[7 * 17];
    __shared__ float Aacc[49];
    __shared__ float Bacc[21];
    __shared__ float parash[21];

    if (tid < 49) Aacc[tid] = 0.f;
    if (tid >= 64 && tid < 85) Bacc[tid - 64] = 0.f;
    __syncthreads();

    const float* wrow = WmT + (size_t)p * 12544;
    for (int ni = 0; ni < 49; ++ni) {
        {
            int t1 = tid >> 4, t2 = tid & 15;
            Msh[t1 * 17 + t2] = wrow[ni * 256 + tid];
        }
        int sy = h + ni / 7 - 3, sx = wpx + ni % 7 - 3;
        bool inb = (sy >= 0 && sy < 48 && sx >= 0 && sx < 48);
        if (tid < 112) {
            int t = tid / 7, c = tid - t * 7;
            Xsh[t * 8 + c] = inb ? design[(size_t)(t * 7 + c) * 2304 + sy * 48 + sx] : 0.f;
        } else if (tid >= 128 && tid < 176) {
            int l = tid - 128;
            int t = l / 3, r = l - t * 3;
            Ysh[t * 4 + r] = inb ? input[(size_t)(t * 10 + r) * 2304 + sy * 48 + sx] : 0.f;
        }
        __syncthreads();
        {
            int t1 = tid >> 4, t2 = tid & 15;
            float s = (t1 == t2) ? 1.f : 0.f;
#pragma unroll
            for (int k = 0; k < 16; ++k) s += Msh[t1 * 17 + k] * Msh[t2 * 17 + k];
            Gsh[t1 * 17 + t2] = s;
        }
        __syncthreads();
        if (tid < 112) {
            int c = tid >> 4, t2 = tid & 15;
            float s = 0.f;
#pragma unroll
            for (int t1 = 0; t1 < 16; ++t1) s += Xsh[t1 * 8 + c] * Gsh[t1 * 17 + t2];
            XTWsh[c * 17 + t2] = s;
        }
        __syncthreads();
        if (tid < 49) {
            int c1 = tid / 7, c2 = tid - c1 * 7;
            float s = 0.f;
#pragma unroll
            for (int t = 0; t < 16; ++t) s += XTWsh[c1 * 17 + t] * Xsh[t * 8 + c2];
            Aacc[tid] += s;
        } else if (tid >= 64 && tid < 85) {
            int l = tid - 64;
            int c = l / 3, r = l - c * 3;
            float s = 0.f;
#pragma unroll
            for (int t = 0; t < 16; ++t) s += XTWsh[c * 17 + t] * Ysh[t * 4 + r];
            Bacc[l] += s;
        }
        __syncthreads();
    }

    if (tid == 0) {
        float Mg[7][10];
#pragma unroll
        for (int i = 0; i < 7; ++i) {
#pragma unroll
            for (int j = 0; j < 7; ++j) Mg[i][j] = Aacc[i * 7 + j] + ((i == j) ? 0.01f : 0.f);
#pragma unroll
            for (int r = 0; r < 3; ++r) Mg[i][7 + r] = Bacc[i * 3 + r];
        }
#pragma unroll
        for (int kk = 0; kk < 7; ++kk) {
            float inv = 1.f / Mg[kk][kk];
#pragma unroll
            for (int j = 0; j < 10; ++j) Mg[kk][j] *= inv;
#pragma unroll
            for (int i = 0; i < 7; ++i) {
                if (i == kk) continue;
                float f = Mg[i][kk];
#pragma unroll
                for (int j = 0; j < 10; ++j) Mg[i][j] -= f * Mg[kk][j];
            }
        }
#pragma unroll
        for (int c = 0; c < 7; ++c)
#pragma unroll
            for (int r = 0; r < 3; ++r) parash[c * 3 + r] = Mg[c][7 + r];
    }
    __syncthreads();

    if (tid < 48) {
        int t = tid / 3, r = tid - t * 3;
        float s = 0.f;
#pragma unroll
        for (int c = 0; c < 7; ++c)
            s += design[(size_t)(t * 7 + c) * 2304 + p] * parash[c * 3 + r];
        out[(size_t)tid * 2304 + p] = s;
    }
}

// ---------------------------------------------------------------------------
extern "C" void kernel_launch(void* const* d_in, const int* in_sizes, int n_in,
                              void* d_out, int out_size, void* d_ws, size_t ws_size,
                              hipStream_t stream) {
    const float* input   = (const float*)d_in[0];
    const float* design  = (const float*)d_in[1];
    const float* fw0     = (const float*)d_in[2];
    const float* fb0     = (const float*)d_in[3];
    const float* fw_rest = (const float*)d_in[4];
    const float* fb_rest = (const float*)d_in[5];
    const float* ww0     = (const float*)d_in[6];
    const float* wb0     = (const float*)d_in[7];
    const float* ww_mid  = (const float*)d_in[8];
    const float* wb_mid  = (const float*)d_in[9];
    const float* ww1     = (const float*)d_in[10];
    const float* wb1     = (const float*)d_in[11];
    const float* ww2     = (const float*)d_in[12];
    const float* wb2     = (const float*)d_in[13];
    float* out = (float*)d_out;
    float* ws = (float*)d_ws;

    // ---- workspace layout (float units; region A [0,28901376) aliases WmT) --
    float* WmT = ws;                                     // fp32 [2304][12544]
    unsigned short* colF  = (unsigned short*)(ws);                  // <=17,104,896 f
    unsigned short* actA  = (unsigned short*)(ws + 17104896);       // 1,843,200 f
    unsigned short* actB  = (unsigned short*)(ws + 18948096);       // 1,843,200 f
    unsigned short* full0 = (unsigned short*)(ws + 20791296);       //   184,320 f
    unsigned short* fw0b  = (unsigned short*)(ws + 20975616);       //     6,144 f
    unsigned short* fwrb  = (unsigned short*)(ws + 20981760);       //   772,096 f (13 x 59392)
    unsigned short* ww0b  = (unsigned short*)(ws + 21753856);       //   819,200 f
    unsigned short* wmb   = (unsigned short*)(ws + 22573056);       // 4,718,592 f (ends 27,291,648)
    unsigned short* g1    = (unsigned short*)(ws + 28901376);       // 7,225,344 f
    unsigned short* ww1b  = (unsigned short*)(ws + 36126720);       // 3,211,264 f (ends 39,337,984)
    // ww2b region (optional, guarded by ws_size): starts at 39,337,984 f
    const size_t WS_BASE_F = 39337984ull;
    unsigned short* ww2b  = (unsigned short*)(ws + WS_BASE_F);

    // ---- weight conversions (except ww_mid: per-layer; ww2: guarded below)
    k_wcvt<10, 9><<<128, 256, 0, stream>>>(fw0, fw0b, 100, 96);
    for (int i = 0; i < 13; ++i)
        k_wcvt<100, 9><<<128, 256, 0, stream>>>(fw_rest + (size_t)i * 90000,
                                                fwrb + (size_t)i * 118784, 100, 928);
    k_wcvt<100, 16><<<1024, 256, 0, stream>>>(ww0, ww0b, 1024, 1600);
    k_wcvt<1024, 1><<<6272, 256, 0, stream>>>(ww1, ww1b, 6272, 1024);

    // ---- feature network: 14 x (im2col + GEMM), pixel-major [36864][100]
    k_build_full<<<1440, 256, 0, stream>>>(input, full0);
    k_im2col3<10><<<36864, 256, 0, stream>>>(full0, colF, 192, 192, 96);
    k_gemm<0, 0><<<dim3(288, 1), 256, 0, stream>>>(fw0b, colF, fb0, actA, 96, 100, 100);
    unsigned short* src = actA;
    unsigned short* dst = actB;
    for (int i = 0; i < 13; ++i) {
        k_im2col3<100><<<36864, 256, 0, stream>>>(src, colF, 192, 192, 928);
        k_gemm<0, 0><<<dim3(288, 1), 256, 0, stream>>>(
            fwrb + (size_t)i * 118784, colF, fb_rest + i * 100, dst, 928, 100, 100);
        unsigned short* t = src; src = dst; dst = t;
    }
    // src == actB (final feature map)

    // ---- weight network head: conv4x4 s4 -> [2304][1024]
    unsigned short* col4 = colF;
    k_im2col4<<<2304, 256, 0, stream>>>(src, col4);
    unsigned short* gA = actA;  // [2304][1024]
    unsigned short* gB = actB;
    k_gemm<0, 0><<<dim3(18, 8), 256, 0, stream>>>(ww0b, col4, wb0, gA, 1600, 1024, 1024);

    // ---- 3 x conv3x3 1024->1024 at 48x48
    unsigned short* gs = gA;
    unsigned short* gd = gB;
    for (int i = 0; i < 3; ++i) {
        k_wcvt<1024, 9><<<1024, 256, 0, stream>>>(ww_mid + (size_t)i * 9437184, wmb, 1024, 9216);
        k_im2col3<1024><<<2304, 256, 0, stream>>>(gs, colF, 48, 48, 9216);
        k_gemm<0, 0><<<dim3(18, 8), 256, 0, stream>>>(wmb, colF, wb_mid + i * 1024, gd, 9216, 1024, 1024);
        unsigned short* t = gs; gs = gd; gd = t;
    }
    // gs == gB (final g)

    // ---- two 1x1 convs (GEMMs)
    k_gemm<0, 0><<<dim3(18, 49), 256, 0, stream>>>(ww1b, gs, wb1, g1, 1024, 6272, 6272);

    // ww2 GEMM: pre-convert A to bf16 when workspace permits (full, then
    // halves), else legacy in-loop-convert fallback.  f2b identical -> same
    // numerics as round-0 kernel.
    const size_t haveF = ws_size / 4;  // floats available
    if (haveF >= WS_BASE_F + 39337984ull) {
        // full convert: [12544][6272] bf16 = 39,337,984 f
        k_cvt_flat<<<76832, 256, 0, stream>>>(ww2, ww2b, (size_t)12544 * 6272);
        k_gemm<1, 1><<<dim3(18, 98), 256, 0, stream>>>(ww2b, g1, wb2, WmT, 6272, 12544, 12544);
    } else if (haveF >= WS_BASE_F + 19668992ull) {
        // two chunks of M=6272 (49 m-tiles each; grid 18x49 = 882 blocks)
        for (int c = 0; c < 2; ++c) {
            k_cvt_flat<<<38416, 256, 0, stream>>>(ww2 + (size_t)c * 6272 * 6272, ww2b,
                                                  (size_t)6272 * 6272);
            k_gemm<1, 1><<<dim3(18, 49), 256, 0, stream>>>(
                ww2b, g1, wb2 + c * 6272, WmT + (size_t)c * 6272, 6272, 6272, 12544);
        }
    } else {
        k_gemm_f32a<1, 1, 1><<<dim3(18, 98), 256, 0, stream>>>(ww2, g1, wb2, WmT, 6272, 12544, 12544);
    }

    // ---- per-pixel solve
    k_solve<<<2304, 256, 0, stream>>>(WmT, design, input, out);
}

// Round 2
// 2536.340 us; speedup vs baseline: 1.3346x; 1.2589x over previous
//
#include <hip/hip_runtime.h>
#include <math.h>

#define LRELU(v) ((v) > 0.f ? (v) : 0.01f * (v))

typedef __attribute__((ext_vector_type(8))) short bf8v;   // 8 x bf16 (4 VGPRs)
typedef __attribute__((ext_vector_type(4))) float f4v;    // MFMA accumulator

// fp32 -> bf16 round-to-nearest-even
static __device__ __forceinline__ unsigned short f2b(float f) {
    unsigned int u = __float_as_uint(f);
    unsigned int r = (u + 0x7fffu + ((u >> 16) & 1u)) >> 16;
    return (unsigned short)r;
}

// async global->LDS, 16B per lane; LDS dest must be linear (base + tid*16).
static __device__ __forceinline__ void gload16(const unsigned short* g, unsigned short* l) {
    __builtin_amdgcn_global_load_lds(
        (__attribute__((address_space(1))) void*)(g),
        (__attribute__((address_space(3))) void*)(l), 16, 0, 0);
}

// ---------------------------------------------------------------------------
// K1: build zero-ring-padded full-res image, pixel-major bf16 [194*194][16]
// (stride 16, channels 10 valid; ring + pads are zero via pre-memset).
// ---------------------------------------------------------------------------
__global__ __launch_bounds__(256) void k_build_full(const float* __restrict__ in,
                                                    unsigned short* __restrict__ full0p) {
    int idx = blockIdx.x * 256 + threadIdx.x;
    if (idx >= 368640) return;
    int c = idx % 10, pix = idx / 10;
    int X = pix % 192, Y = pix / 192;
    int t = (Y & 3) * 4 + (X & 3);
    int h = Y >> 2, w = X >> 2;
    int pp = (Y + 1) * 194 + (X + 1);
    full0p[(size_t)pp * 16 + c] = f2b(in[(((t * 10 + c) * 48) + h) * 48 + w]);
}

// ---------------------------------------------------------------------------
// K2: weight convert+permute fp32 -> bf16.  src (Mv, C, Q) row-major,
// dst [gridDim.x][Kp] with kp = q*CP + c; zero where c>=C or m>=Mv.
// ---------------------------------------------------------------------------
template <int C, int CP, int Q>
__global__ __launch_bounds__(256) void k_wcvt(const float* __restrict__ src,
                                              unsigned short* __restrict__ dst,
                                              int Mv, int Kp) {
    int m = blockIdx.x;
    for (int kp = threadIdx.x; kp < Kp; kp += 256) {
        int qq = kp / CP, c = kp - qq * CP;
        float v = 0.f;
        if (m < Mv && c < C && qq < Q)
            v = src[((size_t)m * C + c) * Q + qq];
        dst[(size_t)m * Kp + kp] = f2b(v);
    }
}

// K2b: flat fp32 -> bf16 convert (identity layout, for 1x1-conv weights)
__global__ __launch_bounds__(256) void k_cvt_flat(const float* __restrict__ src,
                                                  unsigned short* __restrict__ dst,
                                                  size_t n) {
    size_t i = ((size_t)blockIdx.x * 256 + threadIdx.x) * 4;
    if (i >= n) return;
    float4 v = *(const float4*)(src + i);
    ushort4 o;
    o.x = f2b(v.x); o.y = f2b(v.y); o.z = f2b(v.z); o.w = f2b(v.w);
    *(ushort4*)(dst + i) = o;
}

// ---------------------------------------------------------------------------
// K4: im2col 4x4 stride4 from PADDED feature map [194*194][104] (100 valid ch)
// -> dst [2304][1600], kp = (dy*4+dx)*100 + c
// ---------------------------------------------------------------------------
__global__ __launch_bounds__(256) void k_im2col4(const unsigned short* __restrict__ src,
                                                 unsigned short* __restrict__ dst) {
    int p = blockIdx.x;  // 0..2303
    int x = p % 48, y = p / 48;
    for (int kp = threadIdx.x; kp < 1600; kp += 256) {
        int qq = kp / 100, c = kp - qq * 100;
        int yy = y * 4 + (qq >> 2), xx = x * 4 + (qq & 3);
        dst[(size_t)p * 1600 + kp] = src[(size_t)((yy + 1) * 194 + (xx + 1)) * 104 + c];
    }
}

// ---------------------------------------------------------------------------
// K5: MFMA GEMM (m97 structure).  D[m][n] = act(A.Bt + bias[m]) stored
// transposed out[n][m].  REMAP: 0 = plain, 3 = n -> padded 50x50 interior.
// SWZ: bijective XCD-contiguous block swizzle.
// ---------------------------------------------------------------------------
template <int ACT, int OF32, int REMAP, int SWZ>
__global__ __launch_bounds__(256) void k_gemm(
    const unsigned short* __restrict__ A, const unsigned short* __restrict__ Bt,
    const float* __restrict__ bias, void* __restrict__ outv,
    int K, int Mv, int ldout) {
    __shared__ __align__(16) unsigned short As[128 * 32];
    __shared__ __align__(16) unsigned short Bs[128 * 32];
    const int tid = threadIdx.x;
    const int lane = tid & 63;
    const int w = tid >> 6;
    const int wm = w >> 1, wn = w & 1;
    const int q = lane >> 4, ln = lane & 15;
    int bx = blockIdx.x, by = blockIdx.y;
    if (SWZ) {
        int gx = gridDim.x;
        int nwg = gx * gridDim.y;
        int lin = by * gx + bx;
        int qq = nwg >> 3, rr = nwg & 7;
        int xcd = lin & 7, idx = lin >> 3;
        int wg = (xcd < rr ? xcd * (qq + 1) : rr * (qq + 1) + (xcd - rr) * qq) + idx;
        bx = wg % gx; by = wg / gx;
    }
    const int m0 = by * 128, n0 = bx * 128;

    f4v acc[4][4];
#pragma unroll
    for (int i = 0; i < 4; ++i)
#pragma unroll
        for (int j = 0; j < 4; ++j) acc[i][j] = (f4v){0.f, 0.f, 0.f, 0.f};

    const int br0 = tid >> 2, bk0 = (tid & 3) << 3;
    const unsigned short* pA0 = A + (size_t)(m0 + br0) * K + bk0;
    const unsigned short* pA1 = pA0 + (size_t)64 * K;
    const unsigned short* pB0 = Bt + (size_t)(n0 + br0) * K + bk0;
    const unsigned short* pB1 = pB0 + (size_t)64 * K;
    unsigned short* lA0 = As + tid * 8;
    unsigned short* lA1 = As + 2048 + tid * 8;
    unsigned short* lB0 = Bs + tid * 8;
    unsigned short* lB1 = Bs + 2048 + tid * 8;
    const unsigned short* Ap2 = &As[(wm * 64 + ln) * 32 + q * 8];
    const unsigned short* Bp2 = &Bs[(wn * 64 + ln) * 32 + q * 8];

    for (int k0 = 0; k0 < K; k0 += 32) {
        gload16(pA0 + k0, lA0);
        gload16(pA1 + k0, lA1);
        gload16(pB0 + k0, lB0);
        gload16(pB1 + k0, lB1);
        __syncthreads();
        bf8v af[4], bfv[4];
#pragma unroll
        for (int i = 0; i < 4; ++i) af[i] = *(const bf8v*)(Ap2 + i * 512);
#pragma unroll
        for (int j = 0; j < 4; ++j) bfv[j] = *(const bf8v*)(Bp2 + j * 512);
#pragma unroll
        for (int i = 0; i < 4; ++i)
#pragma unroll
            for (int j = 0; j < 4; ++j)
                acc[i][j] = __builtin_amdgcn_mfma_f32_16x16x32_bf16(af[i], bfv[j], acc[i][j], 0, 0, 0);
        __syncthreads();
    }

    float* tb = ((float*)As) + w * 288;
#pragma unroll
    for (int i = 0; i < 4; ++i) {
        const int mbase = m0 + wm * 64 + i * 16;
        float bi[4];
#pragma unroll
        for (int r = 0; r < 4; ++r) {
            int mm = mbase + q * 4 + r;
            bi[r] = (mm < Mv) ? bias[mm] : 0.f;
        }
#pragma unroll
        for (int j = 0; j < 4; ++j) {
            const int nbase = n0 + wn * 64 + j * 16;
#pragma unroll
            for (int r = 0; r < 4; ++r) {
                float v = acc[i][j][r] + bi[r];
                v = ACT ? tanhf(v) : LRELU(v);
                tb[ln * 17 + q * 4 + r] = v;
            }
#pragma unroll
            for (int r = 0; r < 4; ++r) {
                float v = tb[(q * 4 + r) * 17 + ln];
                int n = nbase + q * 4 + r;
                int m = mbase + ln;
                if (m < Mv) {
                    if (REMAP == 3) {
                        int y = n / 48, x = n - y * 48;
                        size_t np = (size_t)((y + 1) * 50 + x + 1);
                        ((unsigned short*)outv)[np * (size_t)ldout + m] = f2b(v);
                    } else {
                        if (OF32) ((float*)outv)[(size_t)n * ldout + m] = v;
                        else ((unsigned short*)outv)[(size_t)n * ldout + m] = f2b(v);
                    }
                }
            }
        }
    }
}

// ---------------------------------------------------------------------------
// K5c: conv3x3-as-GEMM with implicit im2col (shifted-B).  B = padded
// pixel-major activations [rows][CST]; tap (dy,dx) shifts the row index by
// (dy*SH + dx).  A = weights [128m][9*TAPK], zeros at tap-k >= valid C
// (kills the next-pixel channel spill when TAPK > CST).  Output bf16
// out[n][m] with LRELU.  REMAP: 1 = zero ring 194x194 (n>=37636 too),
// 2 = zero ring 50x50 (n>=2500 too), 4 = compact 50x50 interior -> 48x48.
// ---------------------------------------------------------------------------
template <int TAPK, int CST, int SH, int REMAP>
__global__ __launch_bounds__(256) void k_cgemm(
    const unsigned short* __restrict__ A, const unsigned short* __restrict__ Bt,
    const float* __restrict__ bias, unsigned short* __restrict__ outp,
    int Mv, int ldout) {
    __shared__ __align__(16) unsigned short As[128 * 32];
    __shared__ __align__(16) unsigned short Bs[128 * 32];
    const int tid = threadIdx.x;
    const int lane = tid & 63;
    const int w = tid >> 6;
    const int wm = w >> 1, wn = w & 1;
    const int q = lane >> 4, ln = lane & 15;
    const int m0 = blockIdx.y * 128, n0 = blockIdx.x * 128;
    const int KA = 9 * TAPK;

    f4v acc[4][4];
#pragma unroll
    for (int i = 0; i < 4; ++i)
#pragma unroll
        for (int j = 0; j < 4; ++j) acc[i][j] = (f4v){0.f, 0.f, 0.f, 0.f};

    const int br0 = tid >> 2, bk0 = (tid & 3) << 3;
    const unsigned short* pA0 = A + (size_t)(m0 + br0) * KA + bk0;
    const unsigned short* pA1 = pA0 + (size_t)64 * KA;
    unsigned short* lA0 = As + tid * 8;
    unsigned short* lA1 = As + 2048 + tid * 8;
    unsigned short* lB0 = Bs + tid * 8;
    unsigned short* lB1 = Bs + 2048 + tid * 8;
    const unsigned short* Ap2 = &As[(wm * 64 + ln) * 32 + q * 8];
    const unsigned short* Bp2 = &Bs[(wn * 64 + ln) * 32 + q * 8];

#pragma unroll
    for (int tap = 0; tap < 9; ++tap) {
        const int sh = (tap / 3 - 1) * SH + (tap % 3 - 1);
        const unsigned short* pB0 = Bt + (long)(n0 + br0 + sh) * CST + bk0;
        const unsigned short* pB1 = pB0 + (long)64 * CST;
        const int kab = tap * TAPK;
        for (int kk = 0; kk < TAPK; kk += 32) {
            gload16(pA0 + kab + kk, lA0);
            gload16(pA1 + kab + kk, lA1);
            gload16(pB0 + kk, lB0);
            gload16(pB1 + kk, lB1);
            __syncthreads();
            bf8v af[4], bfv[4];
#pragma unroll
            for (int i = 0; i < 4; ++i) af[i] = *(const bf8v*)(Ap2 + i * 512);
#pragma unroll
            for (int j = 0; j < 4; ++j) bfv[j] = *(const bf8v*)(Bp2 + j * 512);
#pragma unroll
            for (int i = 0; i < 4; ++i)
#pragma unroll
                for (int j = 0; j < 4; ++j)
                    acc[i][j] = __builtin_amdgcn_mfma_f32_16x16x32_bf16(af[i], bfv[j], acc[i][j], 0, 0, 0);
            __syncthreads();
        }
    }

    float* tb = ((float*)As) + w * 288;
#pragma unroll
    for (int i = 0; i < 4; ++i) {
        const int mbase = m0 + wm * 64 + i * 16;
        float bi[4];
#pragma unroll
        for (int r = 0; r < 4; ++r) {
            int mm = mbase + q * 4 + r;
            bi[r] = (mm < Mv) ? bias[mm] : 0.f;
        }
#pragma unroll
        for (int j = 0; j < 4; ++j) {
            const int nbase = n0 + wn * 64 + j * 16;
#pragma unroll
            for (int r = 0; r < 4; ++r) {
                float v = acc[i][j][r] + bi[r];
                v = LRELU(v);
                tb[ln * 17 + q * 4 + r] = v;
            }
#pragma unroll
            for (int r = 0; r < 4; ++r) {
                float v = tb[(q * 4 + r) * 17 + ln];
                int n = nbase + q * 4 + r;
                int m = mbase + ln;
                if (m < Mv) {
                    if (REMAP == 1) {
                        int y = n / 194, x = n - y * 194;
                        bool z = (n >= 37636) || y == 0 || y >= 193 || x == 0 || x >= 193;
                        outp[(size_t)n * ldout + m] = f2b(z ? 0.f : v);
                    } else if (REMAP == 2) {
                        int y = n / 50, x = n - y * 50;
                        bool z = (n >= 2500) || y == 0 || y >= 49 || x == 0 || x >= 49;
                        outp[(size_t)n * ldout + m] = f2b(z ? 0.f : v);
                    } else if (REMAP == 4) {
                        int y = n / 50, x = n - y * 50;
                        if (n < 2500 && y >= 1 && y <= 48 && x >= 1 && x <= 48)
                            outp[(size_t)((y - 1) * 48 + (x - 1)) * ldout + m] = f2b(v);
                    }
                }
            }
        }
    }
}

// ---------------------------------------------------------------------------
// K5b: legacy reg-staged GEMM with in-loop fp32->bf16 A conversion (fallback
// for ww2 when workspace is too small to pre-convert). Verified round-0 code.
// ---------------------------------------------------------------------------
template <int ACT, int OF32, int AF32>
__global__ __launch_bounds__(256) void k_gemm_f32a(
    const void* __restrict__ Ain, const unsigned short* __restrict__ Bt,
    const float* __restrict__ bias, void* __restrict__ outv,
    int K, int Mv, int ldout) {
    __shared__ __align__(16) unsigned short As[128 * 40];
    __shared__ __align__(16) unsigned short Bs[128 * 40];
    const int tid = threadIdx.x;
    const int lane = tid & 63;
    const int w = tid >> 6;
    const int wm = w >> 1, wn = w & 1;
    const int q = lane >> 4, ln = lane & 15;
    const int m0 = blockIdx.y * 128, n0 = blockIdx.x * 128;

    f4v acc[4][4];
#pragma unroll
    for (int i = 0; i < 4; ++i)
#pragma unroll
        for (int j = 0; j < 4; ++j) acc[i][j] = (f4v){0.f, 0.f, 0.f, 0.f};

    const int br0 = tid >> 2, bk0 = (tid & 3) << 3;
    const int br1 = br0 + 64;
    const int bl0 = br0 * 40 + bk0, bl1 = br1 * 40 + bk0;
    const unsigned short* pB0 = Bt + (size_t)(n0 + br0) * K + bk0;
    const unsigned short* pB1 = Bt + (size_t)(n0 + br1) * K + bk0;

    const unsigned short* Ab = (const unsigned short*)Ain;
    const float* Af = (const float*)Ain;
    const unsigned short* pA0 = Ab + (size_t)(m0 + br0) * K + bk0;
    const unsigned short* pA1 = Ab + (size_t)(m0 + br1) * K + bk0;
    const int fr = tid >> 3, fk = (tid & 7) << 2;
    const float* pF = Af + (size_t)(m0 + fr) * K + fk;

    for (int k0 = 0; k0 < K; k0 += 32) {
        if (AF32) {
#pragma unroll
            for (int jj = 0; jj < 4; ++jj) {
                float4 v = *(const float4*)(pF + (size_t)jj * 32 * K + k0);
                unsigned int lo = ((unsigned)f2b(v.y) << 16) | f2b(v.x);
                unsigned int hi = ((unsigned)f2b(v.w) << 16) | f2b(v.z);
                *(uint2*)&As[(fr + jj * 32) * 40 + fk] = make_uint2(lo, hi);
            }
        } else {
            uint4 a0 = *(const uint4*)(pA0 + k0);
            uint4 a1 = *(const uint4*)(pA1 + k0);
            *(uint4*)&As[bl0] = a0;
            *(uint4*)&As[bl1] = a1;
        }
        uint4 b0 = *(const uint4*)(pB0 + k0);
        uint4 b1 = *(const uint4*)(pB1 + k0);
        *(uint4*)&Bs[bl0] = b0;
        *(uint4*)&Bs[bl1] = b1;
        __syncthreads();
        const unsigned short* Ap2 = &As[(wm * 64 + ln) * 40 + q * 8];
        const unsigned short* Bp2 = &Bs[(wn * 64 + ln) * 40 + q * 8];
        bf8v af[4], bfv[4];
#pragma unroll
        for (int i = 0; i < 4; ++i) af[i] = *(const bf8v*)(Ap2 + i * 640);
#pragma unroll
        for (int j = 0; j < 4; ++j) bfv[j] = *(const bf8v*)(Bp2 + j * 640);
#pragma unroll
        for (int i = 0; i < 4; ++i)
#pragma unroll
            for (int j = 0; j < 4; ++j)
                acc[i][j] = __builtin_amdgcn_mfma_f32_16x16x32_bf16(af[i], bfv[j], acc[i][j], 0, 0, 0);
        __syncthreads();
    }

    float* tb = ((float*)As) + w * 288;
#pragma unroll
    for (int i = 0; i < 4; ++i) {
        const int mbase = m0 + wm * 64 + i * 16;
        float bi[4];
#pragma unroll
        for (int r = 0; r < 4; ++r) {
            int mm = mbase + q * 4 + r;
            bi[r] = (mm < Mv) ? bias[mm] : 0.f;
        }
#pragma unroll
        for (int j = 0; j < 4; ++j) {
            const int nbase = n0 + wn * 64 + j * 16;
#pragma unroll
            for (int r = 0; r < 4; ++r) {
                float v = acc[i][j][r] + bi[r];
                v = ACT ? tanhf(v) : LRELU(v);
                tb[ln * 17 + q * 4 + r] = v;
            }
#pragma unroll
            for (int r = 0; r < 4; ++r) {
                float v = tb[(q * 4 + r) * 17 + ln];
                size_t n = nbase + q * 4 + r;
                int m = mbase + ln;
                if (m < Mv) {
                    if (OF32) ((float*)outv)[n * (size_t)ldout + m] = v;
                    else ((unsigned short*)outv)[n * (size_t)ldout + m] = f2b(v);
                }
            }
        }
    }
}

// ---------------------------------------------------------------------------
// K6: per-pixel normal equations + solve (verified, unchanged)
// ---------------------------------------------------------------------------
__global__ __launch_bounds__(256) void k_solve(const float* __restrict__ WmT,
                                               const float* __restrict__ design,
                                               const float* __restrict__ input,
                                               float* __restrict__ out) {
    const int p = blockIdx.x;  // 0..2303
    const int h = p / 48, wpx = p % 48;
    const int tid = threadIdx.x;
    __shared__ float Msh[16 * 17];
    __shared__ float Gsh[16 * 17];
    __shared__ float Xsh[16 * 8];
    __shared__ float Ysh[16 * 4];
    __shared__ float XTWsh[7 * 17];
    __shared__ float Aacc[49];
    __shared__ float Bacc[21];
    __shared__ float parash[21];

    if (tid < 49) Aacc[tid] = 0.f;
    if (tid >= 64 && tid < 85) Bacc[tid - 64] = 0.f;
    __syncthreads();

    const float* wrow = WmT + (size_t)p * 12544;
    for (int ni = 0; ni < 49; ++ni) {
        {
            int t1 = tid >> 4, t2 = tid & 15;
            Msh[t1 * 17 + t2] = wrow[ni * 256 + tid];
        }
        int sy = h + ni / 7 - 3, sx = wpx + ni % 7 - 3;
        bool inb = (sy >= 0 && sy < 48 && sx >= 0 && sx < 48);
        if (tid < 112) {
            int t = tid / 7, c = tid - t * 7;
            Xsh[t * 8 + c] = inb ? design[(size_t)(t * 7 + c) * 2304 + sy * 48 + sx] : 0.f;
        } else if (tid >= 128 && tid < 176) {
            int l = tid - 128;
            int t = l / 3, r = l - t * 3;
            Ysh[t * 4 + r] = inb ? input[(size_t)(t * 10 + r) * 2304 + sy * 48 + sx] : 0.f;
        }
        __syncthreads();
        {
            int t1 = tid >> 4, t2 = tid & 15;
            float s = (t1 == t2) ? 1.f : 0.f;
#pragma unroll
            for (int k = 0; k < 16; ++k) s += Msh[t1 * 17 + k] * Msh[t2 * 17 + k];
            Gsh[t1 * 17 + t2] = s;
        }
        __syncthreads();
        if (tid < 112) {
            int c = tid >> 4, t2 = tid & 15;
            float s = 0.f;
#pragma unroll
            for (int t1 = 0; t1 < 16; ++t1) s += Xsh[t1 * 8 + c] * Gsh[t1 * 17 + t2];
            XTWsh[c * 17 + t2] = s;
        }
        __syncthreads();
        if (tid < 49) {
            int c1 = tid / 7, c2 = tid - c1 * 7;
            float s = 0.f;
#pragma unroll
            for (int t = 0; t < 16; ++t) s += XTWsh[c1 * 17 + t] * Xsh[t * 8 + c2];
            Aacc[tid] += s;
        } else if (tid >= 64 && tid < 85) {
            int l = tid - 64;
            int c = l / 3, r = l - c * 3;
            float s = 0.f;
#pragma unroll
            for (int t = 0; t < 16; ++t) s += XTWsh[c * 17 + t] * Ysh[t * 4 + r];
            Bacc[l] += s;
        }
        __syncthreads();
    }

    if (tid == 0) {
        float Mg[7][10];
#pragma unroll
        for (int i = 0; i < 7; ++i) {
#pragma unroll
            for (int j = 0; j < 7; ++j) Mg[i][j] = Aacc[i * 7 + j] + ((i == j) ? 0.01f : 0.f);
#pragma unroll
            for (int r = 0; r < 3; ++r) Mg[i][7 + r] = Bacc[i * 3 + r];
        }
#pragma unroll
        for (int kk = 0; kk < 7; ++kk) {
            float inv = 1.f / Mg[kk][kk];
#pragma unroll
            for (int j = 0; j < 10; ++j) Mg[kk][j] *= inv;
#pragma unroll
            for (int i = 0; i < 7; ++i) {
                if (i == kk) continue;
                float f = Mg[i][kk];
#pragma unroll
                for (int j = 0; j < 10; ++j) Mg[i][j] -= f * Mg[kk][j];
            }
        }
#pragma unroll
        for (int c = 0; c < 7; ++c)
#pragma unroll
            for (int r = 0; r < 3; ++r) parash[c * 3 + r] = Mg[c][7 + r];
    }
    __syncthreads();

    if (tid < 48) {
        int t = tid / 3, r = tid - t * 3;
        float s = 0.f;
#pragma unroll
        for (int c = 0; c < 7; ++c)
            s += design[(size_t)(t * 7 + c) * 2304 + p] * parash[c * 3 + r];
        out[(size_t)tid * 2304 + p] = s;
    }
}

// ---------------------------------------------------------------------------
extern "C" void kernel_launch(void* const* d_in, const int* in_sizes, int n_in,
                              void* d_out, int out_size, void* d_ws, size_t ws_size,
                              hipStream_t stream) {
    const float* input   = (const float*)d_in[0];
    const float* design  = (const float*)d_in[1];
    const float* fw0     = (const float*)d_in[2];
    const float* fb0     = (const float*)d_in[3];
    const float* fw_rest = (const float*)d_in[4];
    const float* fb_rest = (const float*)d_in[5];
    const float* ww0     = (const float*)d_in[6];
    const float* wb0     = (const float*)d_in[7];
    const float* ww_mid  = (const float*)d_in[8];
    const float* wb_mid  = (const float*)d_in[9];
    const float* ww1     = (const float*)d_in[10];
    const float* wb1     = (const float*)d_in[11];
    const float* ww2     = (const float*)d_in[12];
    const float* wb2     = (const float*)d_in[13];
    float* out = (float*)d_out;
    float* ws = (float*)d_ws;

    // ---- workspace layout (float units).  Region [0, 28,901,376) is scratch
    // during the conv phase and becomes WmT (fp32 [2304][12544]) at ww2 time.
    float* WmT = ws;
    unsigned short* full0p = (unsigned short*)(ws + 40000);      // [37956][16] sh
    unsigned short* actPA  = (unsigned short*)(ws + 350000);     // [37956][104] sh
    unsigned short* actPB  = (unsigned short*)(ws + 2330000);    // [37956][104] sh
    unsigned short* fw0c   = (unsigned short*)(ws + 4310000);    // [128][288] sh
    unsigned short* fwrb   = (unsigned short*)(ws + 4330000);    // 13 x [128][1152] sh
    unsigned short* ww0b   = (unsigned short*)(ws + 5290000);    // [1024][1600] sh
    unsigned short* col4   = (unsigned short*)(ws + 6110000);    // [2304][1600] sh
    unsigned short* gPA    = (unsigned short*)(ws + 7960000);    // [2688][1024] sh
    unsigned short* gPB    = (unsigned short*)(ws + 9340000);    // [2688][1024] sh
    unsigned short* wmb    = (unsigned short*)(ws + 10720000);   // [1024][9216] sh
    unsigned short* gcmp   = (unsigned short*)(ws + 15440000);   // [2304][1024] sh
    unsigned short* g1     = (unsigned short*)(ws + 28901376);   // [2304][6272] sh
    unsigned short* ww1b   = (unsigned short*)(ws + 36126720);   // [6272][1024] sh
    const size_t WS_BASE_F = 39337984ull;
    unsigned short* ww2b   = (unsigned short*)(ws + WS_BASE_F);  // [12544][6272] sh

    // ---- zero padded buffers (ring + tails; graph-capture-safe async memset)
    hipMemsetAsync(full0p, 0, (size_t)37956 * 16 * 2, stream);
    hipMemsetAsync(actPA, 0, (size_t)37956 * 104 * 2, stream);
    hipMemsetAsync(actPB, 0, (size_t)37956 * 104 * 2, stream);
    hipMemsetAsync(gPA, 0, (size_t)2688 * 1024 * 2, stream);
    hipMemsetAsync(gPB, 0, (size_t)2688 * 1024 * 2, stream);

    // ---- weight conversions
    k_wcvt<10, 32, 9><<<128, 256, 0, stream>>>(fw0, fw0c, 100, 288);
    for (int i = 0; i < 13; ++i)
        k_wcvt<100, 128, 9><<<128, 256, 0, stream>>>(fw_rest + (size_t)i * 90000,
                                                     fwrb + (size_t)i * 147456, 100, 1152);
    k_wcvt<100, 100, 16><<<1024, 256, 0, stream>>>(ww0, ww0b, 1024, 1600);
    k_wcvt<1024, 1024, 1><<<6272, 256, 0, stream>>>(ww1, ww1b, 6272, 1024);

    // ---- feature network: 14 conv3x3 via implicit-im2col cgemm (padded 194x194)
    k_build_full<<<1440, 256, 0, stream>>>(input, full0p);
    k_cgemm<32, 16, 194, 1><<<dim3(295, 1), 256, 0, stream>>>(fw0c, full0p, fb0, actPA, 100, 104);
    unsigned short* src = actPA;
    unsigned short* dst = actPB;
    for (int i = 0; i < 13; ++i) {
        k_cgemm<128, 104, 194, 1><<<dim3(295, 1), 256, 0, stream>>>(
            fwrb + (size_t)i * 147456, src, fb_rest + i * 100, dst, 100, 104);
        unsigned short* t = src; src = dst; dst = t;
    }
    // src == final feature map (padded)

    // ---- weight network head: conv4x4 s4 -> padded 50x50 [1024]
    k_im2col4<<<2304, 256, 0, stream>>>(src, col4);
    k_gemm<0, 0, 3, 0><<<dim3(18, 8), 256, 0, stream>>>(ww0b, col4, wb0, gPA, 1600, 1024, 1024);

    // ---- 3 x conv3x3 1024->1024 at 48x48 via cgemm on padded 50x50
    k_wcvt<1024, 1024, 9><<<1024, 256, 0, stream>>>(ww_mid, wmb, 1024, 9216);
    k_cgemm<1024, 1024, 50, 2><<<dim3(20, 8), 256, 0, stream>>>(wmb, gPA, wb_mid, gPB, 1024, 1024);
    k_wcvt<1024, 1024, 9><<<1024, 256, 0, stream>>>(ww_mid + (size_t)9437184, wmb, 1024, 9216);
    k_cgemm<1024, 1024, 50, 2><<<dim3(20, 8), 256, 0, stream>>>(wmb, gPB, wb_mid + 1024, gPA, 1024, 1024);
    k_wcvt<1024, 1024, 9><<<1024, 256, 0, stream>>>(ww_mid + (size_t)2 * 9437184, wmb, 1024, 9216);
    k_cgemm<1024, 1024, 50, 4><<<dim3(20, 8), 256, 0, stream>>>(wmb, gPA, wb_mid + 2048, gcmp, 1024, 1024);

    // ---- two 1x1 convs (GEMMs), XCD-swizzled
    k_gemm<0, 0, 0, 1><<<dim3(18, 49), 256, 0, stream>>>(ww1b, gcmp, wb1, g1, 1024, 6272, 6272);

    const size_t haveF = ws_size / 4;
    if (haveF >= WS_BASE_F + 39337984ull) {
        k_cvt_flat<<<76832, 256, 0, stream>>>(ww2, ww2b, (size_t)12544 * 6272);
        k_gemm<1, 1, 0, 1><<<dim3(18, 98), 256, 0, stream>>>(ww2b, g1, wb2, WmT, 6272, 12544, 12544);
    } else if (haveF >= WS_BASE_F + 19668992ull) {
        for (int c = 0; c < 2; ++c) {
            k_cvt_flat<<<38416, 256, 0, stream>>>(ww2 + (size_t)c * 6272 * 6272, ww2b,
                                                  (size_t)6272 * 6272);
            k_gemm<1, 1, 0, 1><<<dim3(18, 49), 256, 0, stream>>>(
                ww2b, g1, wb2 + c * 6272, WmT + (size_t)c * 6272, 6272, 6272, 12544);
        }
    } else {
        k_gemm_f32a<1, 1, 1><<<dim3(18, 98), 256, 0, stream>>>(ww2, g1, wb2, WmT, 6272, 12544, 12544);
    }

    // ---- per-pixel solve
    k_solve<<<2304, 256, 0, stream>>>(WmT, design, input, out);
}

// Round 3
// 2362.038 us; speedup vs baseline: 1.4331x; 1.0738x over previous
//
#include <hip/hip_runtime.h>
#include <math.h>

#define LRELU(v) ((v) > 0.f ? (v) : 0.01f * (v))

typedef __attribute__((ext_vector_type(8))) short bf8v;   // 8 x bf16 (4 VGPRs)
typedef __attribute__((ext_vector_type(4))) float f4v;    // MFMA accumulator

// fp32 -> bf16 round-to-nearest-even
static __device__ __forceinline__ unsigned short f2b(float f) {
    unsigned int u = __float_as_uint(f);
    unsigned int r = (u + 0x7fffu + ((u >> 16) & 1u)) >> 16;
    return (unsigned short)r;
}

// async global->LDS, 16B per lane; LDS dest must be linear (base + tid*16).
static __device__ __forceinline__ void gload16(const unsigned short* g, unsigned short* l) {
    __builtin_amdgcn_global_load_lds(
        (__attribute__((address_space(1))) void*)(g),
        (__attribute__((address_space(3))) void*)(l), 16, 0, 0);
}

// ---------------------------------------------------------------------------
// K1: build zero-ring-padded full-res image, pixel-major bf16 [194*194][16]
// ---------------------------------------------------------------------------
__global__ __launch_bounds__(256) void k_build_full(const float* __restrict__ in,
                                                    unsigned short* __restrict__ full0p) {
    int idx = blockIdx.x * 256 + threadIdx.x;
    if (idx >= 368640) return;
    int c = idx % 10, pix = idx / 10;
    int X = pix % 192, Y = pix / 192;
    int t = (Y & 3) * 4 + (X & 3);
    int h = Y >> 2, w = X >> 2;
    int pp = (Y + 1) * 194 + (X + 1);
    full0p[(size_t)pp * 16 + c] = f2b(in[(((t * 10 + c) * 48) + h) * 48 + w]);
}

// ---------------------------------------------------------------------------
// K2: weight convert+permute fp32 -> bf16.  src (Mv, C, Q) row-major,
// dst [gridDim.x][Kp] with kp = q*CP + c; zero where c>=C or m>=Mv.
// ---------------------------------------------------------------------------
template <int C, int CP, int Q>
__global__ __launch_bounds__(256) void k_wcvt(const float* __restrict__ src,
                                              unsigned short* __restrict__ dst,
                                              int Mv, int Kp) {
    int m = blockIdx.x;
    for (int kp = threadIdx.x; kp < Kp; kp += 256) {
        int qq = kp / CP, c = kp - qq * CP;
        float v = 0.f;
        if (m < Mv && c < C && qq < Q)
            v = src[((size_t)m * C + c) * Q + qq];
        dst[(size_t)m * Kp + kp] = f2b(v);
    }
}

// K2b: flat fp32 -> bf16 convert (identity layout, for 1x1-conv weights)
__global__ __launch_bounds__(256) void k_cvt_flat(const float* __restrict__ src,
                                                  unsigned short* __restrict__ dst,
                                                  size_t n) {
    size_t i = ((size_t)blockIdx.x * 256 + threadIdx.x) * 4;
    if (i >= n) return;
    float4 v = *(const float4*)(src + i);
    ushort4 o;
    o.x = f2b(v.x); o.y = f2b(v.y); o.z = f2b(v.z); o.w = f2b(v.w);
    *(ushort4*)(dst + i) = o;
}

// ---------------------------------------------------------------------------
// K4: im2col 4x4 stride4 from PADDED feature map [194*194][104]
// ---------------------------------------------------------------------------
__global__ __launch_bounds__(256) void k_im2col4(const unsigned short* __restrict__ src,
                                                 unsigned short* __restrict__ dst) {
    int p = blockIdx.x;  // 0..2303
    int x = p % 48, y = p / 48;
    for (int kp = threadIdx.x; kp < 1600; kp += 256) {
        int qq = kp / 100, c = kp - qq * 100;
        int yy = y * 4 + (qq >> 2), xx = x * 4 + (qq & 3);
        dst[(size_t)p * 1600 + kp] = src[(size_t)((yy + 1) * 194 + (xx + 1)) * 104 + c];
    }
}

// ---------------------------------------------------------------------------
// K5: MFMA GEMM (m97 2-phase structure) — kept for head gemm + fallbacks.
// ---------------------------------------------------------------------------
template <int ACT, int OF32, int REMAP, int SWZ>
__global__ __launch_bounds__(256) void k_gemm(
    const unsigned short* __restrict__ A, const unsigned short* __restrict__ Bt,
    const float* __restrict__ bias, void* __restrict__ outv,
    int K, int Mv, int ldout) {
    __shared__ __align__(16) unsigned short As[128 * 32];
    __shared__ __align__(16) unsigned short Bs[128 * 32];
    const int tid = threadIdx.x;
    const int lane = tid & 63;
    const int w = tid >> 6;
    const int wm = w >> 1, wn = w & 1;
    const int q = lane >> 4, ln = lane & 15;
    int bx = blockIdx.x, by = blockIdx.y;
    if (SWZ) {
        int gx = gridDim.x;
        int nwg = gx * gridDim.y;
        int lin = by * gx + bx;
        int qq = nwg >> 3, rr = nwg & 7;
        int xcd = lin & 7, idx = lin >> 3;
        int wg = (xcd < rr ? xcd * (qq + 1) : rr * (qq + 1) + (xcd - rr) * qq) + idx;
        bx = wg % gx; by = wg / gx;
    }
    const int m0 = by * 128, n0 = bx * 128;

    f4v acc[4][4];
#pragma unroll
    for (int i = 0; i < 4; ++i)
#pragma unroll
        for (int j = 0; j < 4; ++j) acc[i][j] = (f4v){0.f, 0.f, 0.f, 0.f};

    const int br0 = tid >> 2, bk0 = (tid & 3) << 3;
    const unsigned short* pA0 = A + (size_t)(m0 + br0) * K + bk0;
    const unsigned short* pA1 = pA0 + (size_t)64 * K;
    const unsigned short* pB0 = Bt + (size_t)(n0 + br0) * K + bk0;
    const unsigned short* pB1 = pB0 + (size_t)64 * K;
    unsigned short* lA0 = As + tid * 8;
    unsigned short* lA1 = As + 2048 + tid * 8;
    unsigned short* lB0 = Bs + tid * 8;
    unsigned short* lB1 = Bs + 2048 + tid * 8;
    const unsigned short* Ap2 = &As[(wm * 64 + ln) * 32 + q * 8];
    const unsigned short* Bp2 = &Bs[(wn * 64 + ln) * 32 + q * 8];

    for (int k0 = 0; k0 < K; k0 += 32) {
        gload16(pA0 + k0, lA0);
        gload16(pA1 + k0, lA1);
        gload16(pB0 + k0, lB0);
        gload16(pB1 + k0, lB1);
        __syncthreads();
        bf8v af[4], bfv[4];
#pragma unroll
        for (int i = 0; i < 4; ++i) af[i] = *(const bf8v*)(Ap2 + i * 512);
#pragma unroll
        for (int j = 0; j < 4; ++j) bfv[j] = *(const bf8v*)(Bp2 + j * 512);
#pragma unroll
        for (int i = 0; i < 4; ++i)
#pragma unroll
            for (int j = 0; j < 4; ++j)
                acc[i][j] = __builtin_amdgcn_mfma_f32_16x16x32_bf16(af[i], bfv[j], acc[i][j], 0, 0, 0);
        __syncthreads();
    }

    float* tb = ((float*)As) + w * 288;
#pragma unroll
    for (int i = 0; i < 4; ++i) {
        const int mbase = m0 + wm * 64 + i * 16;
        float bi[4];
#pragma unroll
        for (int r = 0; r < 4; ++r) {
            int mm = mbase + q * 4 + r;
            bi[r] = (mm < Mv) ? bias[mm] : 0.f;
        }
#pragma unroll
        for (int j = 0; j < 4; ++j) {
            const int nbase = n0 + wn * 64 + j * 16;
#pragma unroll
            for (int r = 0; r < 4; ++r) {
                float v = acc[i][j][r] + bi[r];
                v = ACT ? tanhf(v) : LRELU(v);
                tb[ln * 17 + q * 4 + r] = v;
            }
#pragma unroll
            for (int r = 0; r < 4; ++r) {
                float v = tb[(q * 4 + r) * 17 + ln];
                int n = nbase + q * 4 + r;
                int m = mbase + ln;
                if (m < Mv) {
                    if (REMAP == 3) {
                        int y = n / 48, x = n - y * 48;
                        size_t np = (size_t)((y + 1) * 50 + x + 1);
                        ((unsigned short*)outv)[np * (size_t)ldout + m] = f2b(v);
                    } else {
                        if (OF32) ((float*)outv)[(size_t)n * ldout + m] = v;
                        else ((unsigned short*)outv)[(size_t)n * ldout + m] = f2b(v);
                    }
                }
            }
        }
    }
}

// ---------------------------------------------------------------------------
// K5big: 256x256 deep-pipelined MFMA GEMM (T2 swizzle + T3/T4 counted vmcnt +
// T5 setprio).  512 thr = 8 waves (2M x 4N), BK=64, LDS 128 KiB dbuf.
// Requires: M % 256 == 0 (A zero-padded rows), N % 256 == 0, K % 64 == 0.
// Per K-tile t: ds_read all 24 frags of buf[cur] -> MFMA ks0 (overlaps ks1
// ds_reads) -> lgkmcnt(0); barrier -> stage tile t+2 into buf[cur] ->
// vmcnt(8) (tile t+1 landed, t+2 stays in flight) ; barrier -> MFMA ks1.
// Accumulation order per output element identical to k_gemm (k ascending).
// LDS swizzle: 16B-chunk j stored at j ^ (row&7); read addr uses the same
// XOR (row&7 == lane&7 for every fragment row) -> conflict-free ds_read_b128.
// ---------------------------------------------------------------------------
template <int ACT, int OF32, int SWZ>
__global__ __launch_bounds__(512, 1) void k_gemm256(
    const unsigned short* __restrict__ A, const unsigned short* __restrict__ Bt,
    const float* __restrict__ bias, void* __restrict__ outv,
    int K, int Mv, int ldout) {
    __shared__ __align__(16) unsigned short As[2][16384];
    __shared__ __align__(16) unsigned short Bs[2][16384];
    const int tid = threadIdx.x;          // 0..511
    const int lane = tid & 63;
    const int w = tid >> 6;               // 0..7
    const int wm = w >> 2;                // 0..1
    const int wn = w & 3;                 // 0..3
    const int q = lane >> 4, ln = lane & 15;

    int bx = blockIdx.x, by = blockIdx.y;
    if (SWZ) {
        int gx = gridDim.x;
        int nwg = gx * gridDim.y;
        int lin = by * gx + bx;
        int qq = nwg >> 3, rr = nwg & 7;
        int xcd = lin & 7, idx = lin >> 3;
        int wg = (xcd < rr ? xcd * (qq + 1) : rr * (qq + 1) + (xcd - rr) * qq) + idx;
        bx = wg % gx; by = wg / gx;
    }
    const int m0 = by * 256, n0 = bx * 256;

    f4v acc[8][4];
#pragma unroll
    for (int i = 0; i < 8; ++i)
#pragma unroll
        for (int j = 0; j < 4; ++j) acc[i][j] = (f4v){0.f, 0.f, 0.f, 0.f};

    // ---- staging: chunk c = r*512+tid -> row r*64 + (tid>>3), 16B-chunk tid&7
    const int srow = tid >> 3;            // 0..63
    const int sj = tid & 7;
    const int sjx = sj ^ (srow & 7);      // pre-swizzled source chunk (involution)
    const unsigned short* gA = A + (size_t)(m0 + srow) * K + sjx * 8;
    const unsigned short* gB = Bt + (size_t)(n0 + srow) * K + sjx * 8;
    const size_t rstride = (size_t)64 * K;
    unsigned short* lA = &As[0][0] + tid * 8;   // +buf*16384, +r*4096
    unsigned short* lB = &Bs[0][0] + tid * 8;

#define STAGE256(buf, t)                                               \
    {                                                                  \
        const unsigned short* ga_ = gA + (size_t)(t) * 64;             \
        const unsigned short* gb_ = gB + (size_t)(t) * 64;             \
        unsigned short* la_ = lA + (buf) * 16384;                      \
        unsigned short* lb_ = lB + (buf) * 16384;                      \
        _Pragma("unroll")                                              \
        for (int r_ = 0; r_ < 4; ++r_) {                               \
            gload16(ga_ + r_ * rstride, la_ + r_ * 4096);              \
            gload16(gb_ + r_ * rstride, lb_ + r_ * 4096);              \
        }                                                              \
    }

    // ---- read offsets (elts).  row&7 == ln&7 for all fragment rows.
    int aoff[8], boff[4];
#pragma unroll
    for (int mf = 0; mf < 8; ++mf) aoff[mf] = (wm * 128 + mf * 16 + ln) * 64;
#pragma unroll
    for (int nf = 0; nf < 4; ++nf) boff[nf] = (wn * 64 + nf * 16 + ln) * 64;
    const int l7 = ln & 7;
    const int koff0 = ((0 * 4 + q) ^ l7) * 8;   // ks=0
    const int koff1 = ((1 * 4 + q) ^ l7) * 8;   // ks=1

    const int NT = K >> 6;
    STAGE256(0, 0);
    STAGE256(1, 1);
    asm volatile("s_waitcnt vmcnt(8)" ::: "memory");
    __builtin_amdgcn_sched_barrier(0);
    __builtin_amdgcn_s_barrier();

    for (int t = 0; t < NT; ++t) {
        const int cur = t & 1;
        const unsigned short* as = &As[cur][0];
        const unsigned short* bs = &Bs[cur][0];
        bf8v a0[8], b0[4], a1[8], b1[4];
#pragma unroll
        for (int mf = 0; mf < 8; ++mf) a0[mf] = *(const bf8v*)&as[aoff[mf] + koff0];
#pragma unroll
        for (int nf = 0; nf < 4; ++nf) b0[nf] = *(const bf8v*)&bs[boff[nf] + koff0];
#pragma unroll
        for (int mf = 0; mf < 8; ++mf) a1[mf] = *(const bf8v*)&as[aoff[mf] + koff1];
#pragma unroll
        for (int nf = 0; nf < 4; ++nf) b1[nf] = *(const bf8v*)&bs[boff[nf] + koff1];
        __builtin_amdgcn_s_setprio(1);
#pragma unroll
        for (int mf = 0; mf < 8; ++mf)
#pragma unroll
            for (int nf = 0; nf < 4; ++nf)
                acc[mf][nf] = __builtin_amdgcn_mfma_f32_16x16x32_bf16(a0[mf], b0[nf], acc[mf][nf], 0, 0, 0);
        __builtin_amdgcn_s_setprio(0);
        // all ds_reads of buf[cur] complete before anyone overwrites it
        asm volatile("s_waitcnt lgkmcnt(0)" ::: "memory");
        __builtin_amdgcn_sched_barrier(0);
        __builtin_amdgcn_s_barrier();
        if (t + 2 < NT) {
            STAGE256(cur, t + 2);
            asm volatile("s_waitcnt vmcnt(8)" ::: "memory");  // tile t+1 landed
        } else {
            asm volatile("s_waitcnt vmcnt(0)" ::: "memory");
        }
        __builtin_amdgcn_sched_barrier(0);
        __builtin_amdgcn_s_barrier();
        __builtin_amdgcn_s_setprio(1);
#pragma unroll
        for (int mf = 0; mf < 8; ++mf)
#pragma unroll
            for (int nf = 0; nf < 4; ++nf)
                acc[mf][nf] = __builtin_amdgcn_mfma_f32_16x16x32_bf16(a1[mf], b1[nf], acc[mf][nf], 0, 0, 0);
        __builtin_amdgcn_s_setprio(0);
    }
    __builtin_amdgcn_s_barrier();
#undef STAGE256

    // ---- transposed epilogue, per-wave 16x17 tile (intra-wave only)
    float* tb = ((float*)&As[0][0]) + w * 288;
#pragma unroll
    for (int mf = 0; mf < 8; ++mf) {
        const int mbase = m0 + wm * 128 + mf * 16;
        float bi[4];
#pragma unroll
        for (int r = 0; r < 4; ++r) {
            int mm = mbase + q * 4 + r;
            bi[r] = (mm < Mv) ? bias[mm] : 0.f;
        }
#pragma unroll
        for (int nf = 0; nf < 4; ++nf) {
            const int nbase = n0 + wn * 64 + nf * 16;
#pragma unroll
            for (int r = 0; r < 4; ++r) {
                float v = acc[mf][nf][r] + bi[r];
                v = ACT ? tanhf(v) : LRELU(v);
                tb[ln * 17 + q * 4 + r] = v;
            }
#pragma unroll
            for (int r = 0; r < 4; ++r) {
                float v = tb[(q * 4 + r) * 17 + ln];
                int n = nbase + q * 4 + r;
                int m = mbase + ln;
                if (m < Mv) {
                    if (OF32) ((float*)outv)[(size_t)n * ldout + m] = v;
                    else ((unsigned short*)outv)[(size_t)n * ldout + m] = f2b(v);
                }
            }
        }
    }
}

// ---------------------------------------------------------------------------
// K5c: conv3x3-as-GEMM with implicit im2col (shifted-B).  (round-2, verified)
// ---------------------------------------------------------------------------
template <int TAPK, int CST, int SH, int REMAP>
__global__ __launch_bounds__(256) void k_cgemm(
    const unsigned short* __restrict__ A, const unsigned short* __restrict__ Bt,
    const float* __restrict__ bias, unsigned short* __restrict__ outp,
    int Mv, int ldout) {
    __shared__ __align__(16) unsigned short As[128 * 32];
    __shared__ __align__(16) unsigned short Bs[128 * 32];
    const int tid = threadIdx.x;
    const int lane = tid & 63;
    const int w = tid >> 6;
    const int wm = w >> 1, wn = w & 1;
    const int q = lane >> 4, ln = lane & 15;
    const int m0 = blockIdx.y * 128, n0 = blockIdx.x * 128;
    const int KA = 9 * TAPK;

    f4v acc[4][4];
#pragma unroll
    for (int i = 0; i < 4; ++i)
#pragma unroll
        for (int j = 0; j < 4; ++j) acc[i][j] = (f4v){0.f, 0.f, 0.f, 0.f};

    const int br0 = tid >> 2, bk0 = (tid & 3) << 3;
    const unsigned short* pA0 = A + (size_t)(m0 + br0) * KA + bk0;
    const unsigned short* pA1 = pA0 + (size_t)64 * KA;
    unsigned short* lA0 = As + tid * 8;
    unsigned short* lA1 = As + 2048 + tid * 8;
    unsigned short* lB0 = Bs + tid * 8;
    unsigned short* lB1 = Bs + 2048 + tid * 8;
    const unsigned short* Ap2 = &As[(wm * 64 + ln) * 32 + q * 8];
    const unsigned short* Bp2 = &Bs[(wn * 64 + ln) * 32 + q * 8];

#pragma unroll
    for (int tap = 0; tap < 9; ++tap) {
        const int sh = (tap / 3 - 1) * SH + (tap % 3 - 1);
        const unsigned short* pB0 = Bt + (long)(n0 + br0 + sh) * CST + bk0;
        const unsigned short* pB1 = pB0 + (long)64 * CST;
        const int kab = tap * TAPK;
        for (int kk = 0; kk < TAPK; kk += 32) {
            gload16(pA0 + kab + kk, lA0);
            gload16(pA1 + kab + kk, lA1);
            gload16(pB0 + kk, lB0);
            gload16(pB1 + kk, lB1);
            __syncthreads();
            bf8v af[4], bfv[4];
#pragma unroll
            for (int i = 0; i < 4; ++i) af[i] = *(const bf8v*)(Ap2 + i * 512);
#pragma unroll
            for (int j = 0; j < 4; ++j) bfv[j] = *(const bf8v*)(Bp2 + j * 512);
#pragma unroll
            for (int i = 0; i < 4; ++i)
#pragma unroll
                for (int j = 0; j < 4; ++j)
                    acc[i][j] = __builtin_amdgcn_mfma_f32_16x16x32_bf16(af[i], bfv[j], acc[i][j], 0, 0, 0);
            __syncthreads();
        }
    }

    float* tb = ((float*)As) + w * 288;
#pragma unroll
    for (int i = 0; i < 4; ++i) {
        const int mbase = m0 + wm * 64 + i * 16;
        float bi[4];
#pragma unroll
        for (int r = 0; r < 4; ++r) {
            int mm = mbase + q * 4 + r;
            bi[r] = (mm < Mv) ? bias[mm] : 0.f;
        }
#pragma unroll
        for (int j = 0; j < 4; ++j) {
            const int nbase = n0 + wn * 64 + j * 16;
#pragma unroll
            for (int r = 0; r < 4; ++r) {
                float v = acc[i][j][r] + bi[r];
                v = LRELU(v);
                tb[ln * 17 + q * 4 + r] = v;
            }
#pragma unroll
            for (int r = 0; r < 4; ++r) {
                float v = tb[(q * 4 + r) * 17 + ln];
                int n = nbase + q * 4 + r;
                int m = mbase + ln;
                if (m < Mv) {
                    if (REMAP == 1) {
                        int y = n / 194, x = n - y * 194;
                        bool z = (n >= 37636) || y == 0 || y >= 193 || x == 0 || x >= 193;
                        outp[(size_t)n * ldout + m] = f2b(z ? 0.f : v);
                    } else if (REMAP == 2) {
                        int y = n / 50, x = n - y * 50;
                        bool z = (n >= 2500) || y == 0 || y >= 49 || x == 0 || x >= 49;
                        outp[(size_t)n * ldout + m] = f2b(z ? 0.f : v);
                    } else if (REMAP == 4) {
                        int y = n / 50, x = n - y * 50;
                        if (n < 2500 && y >= 1 && y <= 48 && x >= 1 && x <= 48)
                            outp[(size_t)((y - 1) * 48 + (x - 1)) * ldout + m] = f2b(v);
                    }
                }
            }
        }
    }
}

// ---------------------------------------------------------------------------
// K5b: legacy reg-staged GEMM with in-loop fp32->bf16 A conversion (fallback)
// ---------------------------------------------------------------------------
template <int ACT, int OF32, int AF32>
__global__ __launch_bounds__(256) void k_gemm_f32a(
    const void* __restrict__ Ain, const unsigned short* __restrict__ Bt,
    const float* __restrict__ bias, void* __restrict__ outv,
    int K, int Mv, int ldout) {
    __shared__ __align__(16) unsigned short As[128 * 40];
    __shared__ __align__(16) unsigned short Bs[128 * 40];
    const int tid = threadIdx.x;
    const int lane = tid & 63;
    const int w = tid >> 6;
    const int wm = w >> 1, wn = w & 1;
    const int q = lane >> 4, ln = lane & 15;
    const int m0 = blockIdx.y * 128, n0 = blockIdx.x * 128;

    f4v acc[4][4];
#pragma unroll
    for (int i = 0; i < 4; ++i)
#pragma unroll
        for (int j = 0; j < 4; ++j) acc[i][j] = (f4v){0.f, 0.f, 0.f, 0.f};

    const int br0 = tid >> 2, bk0 = (tid & 3) << 3;
    const int br1 = br0 + 64;
    const int bl0 = br0 * 40 + bk0, bl1 = br1 * 40 + bk0;
    const unsigned short* pB0 = Bt + (size_t)(n0 + br0) * K + bk0;
    const unsigned short* pB1 = Bt + (size_t)(n0 + br1) * K + bk0;

    const unsigned short* Ab = (const unsigned short*)Ain;
    const float* Af = (const float*)Ain;
    const unsigned short* pA0 = Ab + (size_t)(m0 + br0) * K + bk0;
    const unsigned short* pA1 = Ab + (size_t)(m0 + br1) * K + bk0;
    const int fr = tid >> 3, fk = (tid & 7) << 2;
    const float* pF = Af + (size_t)(m0 + fr) * K + fk;

    for (int k0 = 0; k0 < K; k0 += 32) {
        if (AF32) {
#pragma unroll
            for (int jj = 0; jj < 4; ++jj) {
                float4 v = *(const float4*)(pF + (size_t)jj * 32 * K + k0);
                unsigned int lo = ((unsigned)f2b(v.y) << 16) | f2b(v.x);
                unsigned int hi = ((unsigned)f2b(v.w) << 16) | f2b(v.z);
                *(uint2*)&As[(fr + jj * 32) * 40 + fk] = make_uint2(lo, hi);
            }
        } else {
            uint4 a0 = *(const uint4*)(pA0 + k0);
            uint4 a1 = *(const uint4*)(pA1 + k0);
            *(uint4*)&As[bl0] = a0;
            *(uint4*)&As[bl1] = a1;
        }
        uint4 b0 = *(const uint4*)(pB0 + k0);
        uint4 b1 = *(const uint4*)(pB1 + k0);
        *(uint4*)&Bs[bl0] = b0;
        *(uint4*)&Bs[bl1] = b1;
        __syncthreads();
        const unsigned short* Ap2 = &As[(wm * 64 + ln) * 40 + q * 8];
        const unsigned short* Bp2 = &Bs[(wn * 64 + ln) * 40 + q * 8];
        bf8v af[4], bfv[4];
#pragma unroll
        for (int i = 0; i < 4; ++i) af[i] = *(const bf8v*)(Ap2 + i * 640);
#pragma unroll
        for (int j = 0; j < 4; ++j) bfv[j] = *(const bf8v*)(Bp2 + j * 640);
#pragma unroll
        for (int i = 0; i < 4; ++i)
#pragma unroll
            for (int j = 0; j < 4; ++j)
                acc[i][j] = __builtin_amdgcn_mfma_f32_16x16x32_bf16(af[i], bfv[j], acc[i][j], 0, 0, 0);
        __syncthreads();
    }

    float* tb = ((float*)As) + w * 288;
#pragma unroll
    for (int i = 0; i < 4; ++i) {
        const int mbase = m0 + wm * 64 + i * 16;
        float bi[4];
#pragma unroll
        for (int r = 0; r < 4; ++r) {
            int mm = mbase + q * 4 + r;
            bi[r] = (mm < Mv) ? bias[mm] : 0.f;
        }
#pragma unroll
        for (int j = 0; j < 4; ++j) {
            const int nbase = n0 + wn * 64 + j * 16;
#pragma unroll
            for (int r = 0; r < 4; ++r) {
                float v = acc[i][j][r] + bi[r];
                v = ACT ? tanhf(v) : LRELU(v);
                tb[ln * 17 + q * 4 + r] = v;
            }
#pragma unroll
            for (int r = 0; r < 4; ++r) {
                float v = tb[(q * 4 + r) * 17 + ln];
                size_t n = nbase + q * 4 + r;
                int m = mbase + ln;
                if (m < Mv) {
                    if (OF32) ((float*)outv)[n * (size_t)ldout + m] = v;
                    else ((unsigned short*)outv)[n * (size_t)ldout + m] = f2b(v);
                }
            }
        }
    }
}

// ---------------------------------------------------------------------------
// K6: per-pixel normal equations + solve (verified, unchanged)
// ---------------------------------------------------------------------------
__global__ __launch_bounds__(256) void k_solve(const float* __restrict__ WmT,
                                               const float* __restrict__ design,
                                               const float* __restrict__ input,
                                               float* __restrict__ out) {
    const int p = blockIdx.x;  // 0..2303
    const int h = p / 48, wpx = p % 48;
    const int tid = threadIdx.x;
    __shared__ float Msh[16 * 17];
    __shared__ float Gsh[16 * 17];
    __shared__ float Xsh[16 * 8];
    __shared__ float Ysh[16 * 4];
    __shared__ float XTWsh[7 * 17];
    __shared__ float Aacc[49];
    __shared__ float Bacc[21];
    __shared__ float parash[21];

    if (tid < 49) Aacc[tid] = 0.f;
    if (tid >= 64 && tid < 85) Bacc[tid - 64] = 0.f;
    __syncthreads();

    const float* wrow = WmT + (size_t)p * 12544;
    for (int ni = 0; ni < 49; ++ni) {
        {
            int t1 = tid >> 4, t2 = tid & 15;
            Msh[t1 * 17 + t2] = wrow[ni * 256 + tid];
        }
        int sy = h + ni / 7 - 3, sx = wpx + ni % 7 - 3;
        bool inb = (sy >= 0 && sy < 48 && sx >= 0 && sx < 48);
        if (tid < 112) {
            int t = tid / 7, c = tid - t * 7;
            Xsh[t * 8 + c] = inb ? design[(size_t)(t * 7 + c) * 2304 + sy * 48 + sx] : 0.f;
        } else if (tid >= 128 && tid < 176) {
            int l = tid - 128;
            int t = l / 3, r = l - t * 3;
            Ysh[t * 4 + r] = inb ? input[(size_t)(t * 10 + r) * 2304 + sy * 48 + sx] : 0.f;
        }
        __syncthreads();
        {
            int t1 = tid >> 4, t2 = tid & 15;
            float s = (t1 == t2) ? 1.f : 0.f;
#pragma unroll
            for (int k = 0; k < 16; ++k) s += Msh[t1 * 17 + k] * Msh[t2 * 17 + k];
            Gsh[t1 * 17 + t2] = s;
        }
        __syncthreads();
        if (tid < 112) {
            int c = tid >> 4, t2 = tid & 15;
            float s = 0.f;
#pragma unroll
            for (int t1 = 0; t1 < 16; ++t1) s += Xsh[t1 * 8 + c] * Gsh[t1 * 17 + t2];
            XTWsh[c * 17 + t2] = s;
        }
        __syncthreads();
        if (tid < 49) {
            int c1 = tid / 7, c2 = tid - c1 * 7;
            float s = 0.f;
#pragma unroll
            for (int t = 0; t < 16; ++t) s += XTWsh[c1 * 17 + t] * Xsh[t * 8 + c2];
            Aacc[tid] += s;
        } else if (tid >= 64 && tid < 85) {
            int l = tid - 64;
            int c = l / 3, r = l - c * 3;
            float s = 0.f;
#pragma unroll
            for (int t = 0; t < 16; ++t) s += XTWsh[c * 17 + t] * Ysh[t * 4 + r];
            Bacc[l] += s;
        }
        __syncthreads();
    }

    if (tid == 0) {
        float Mg[7][10];
#pragma unroll
        for (int i = 0; i < 7; ++i) {
#pragma unroll
            for (int j = 0; j < 7; ++j) Mg[i][j] = Aacc[i * 7 + j] + ((i == j) ? 0.01f : 0.f);
#pragma unroll
            for (int r = 0; r < 3; ++r) Mg[i][7 + r] = Bacc[i * 3 + r];
        }
#pragma unroll
        for (int kk = 0; kk < 7; ++kk) {
            float inv = 1.f / Mg[kk][kk];
#pragma unroll
            for (int j = 0; j < 10; ++j) Mg[kk][j] *= inv;
#pragma unroll
            for (int i = 0; i < 7; ++i) {
                if (i == kk) continue;
                float f = Mg[i][kk];
#pragma unroll
                for (int j = 0; j < 10; ++j) Mg[i][j] -= f * Mg[kk][j];
            }
        }
#pragma unroll
        for (int c = 0; c < 7; ++c)
#pragma unroll
            for (int r = 0; r < 3; ++r) parash[c * 3 + r] = Mg[c][7 + r];
    }
    __syncthreads();

    if (tid < 48) {
        int t = tid / 3, r = tid - t * 3;
        float s = 0.f;
#pragma unroll
        for (int c = 0; c < 7; ++c)
            s += design[(size_t)(t * 7 + c) * 2304 + p] * parash[c * 3 + r];
        out[(size_t)tid * 2304 + p] = s;
    }
}

// ---------------------------------------------------------------------------
extern "C" void kernel_launch(void* const* d_in, const int* in_sizes, int n_in,
                              void* d_out, int out_size, void* d_ws, size_t ws_size,
                              hipStream_t stream) {
    const float* input   = (const float*)d_in[0];
    const float* design  = (const float*)d_in[1];
    const float* fw0     = (const float*)d_in[2];
    const float* fb0     = (const float*)d_in[3];
    const float* fw_rest = (const float*)d_in[4];
    const float* fb_rest = (const float*)d_in[5];
    const float* ww0     = (const float*)d_in[6];
    const float* wb0     = (const float*)d_in[7];
    const float* ww_mid  = (const float*)d_in[8];
    const float* wb_mid  = (const float*)d_in[9];
    const float* ww1     = (const float*)d_in[10];
    const float* wb1     = (const float*)d_in[11];
    const float* ww2     = (const float*)d_in[12];
    const float* wb2     = (const float*)d_in[13];
    float* out = (float*)d_out;
    float* ws = (float*)d_ws;

    // ---- workspace layout (float units).  Region [0, 28,901,376) is scratch
    // during the conv phase and becomes WmT (fp32 [2304][12544]) at ww2 time.
    float* WmT = ws;
    unsigned short* full0p = (unsigned short*)(ws + 40000);      // [37956][16] sh
    unsigned short* actPA  = (unsigned short*)(ws + 350000);     // [37956][104] sh
    unsigned short* actPB  = (unsigned short*)(ws + 2330000);    // [37956][104] sh
    unsigned short* fw0c   = (unsigned short*)(ws + 4310000);    // [128][288] sh
    unsigned short* fwrb   = (unsigned short*)(ws + 4330000);    // 13 x [128][1152] sh
    unsigned short* ww0b   = (unsigned short*)(ws + 5290000);    // [1024][1600] sh
    unsigned short* col4   = (unsigned short*)(ws + 6110000);    // [2304][1600] sh
    unsigned short* gPA    = (unsigned short*)(ws + 7960000);    // [2688][1024] sh
    unsigned short* gPB    = (unsigned short*)(ws + 9340000);    // [2688][1024] sh
    unsigned short* wmb    = (unsigned short*)(ws + 10720000);   // [1024][9216] sh
    unsigned short* gcmp   = (unsigned short*)(ws + 15440000);   // [2304][1024] sh
    unsigned short* g1     = (unsigned short*)(ws + 28901376);   // [2304][6272] sh
    unsigned short* ww1b   = (unsigned short*)(ws + 36126720);   // fallback slot
    const size_t WS_BASE_F = 39337984ull;
    unsigned short* ww2b   = (unsigned short*)(ws + WS_BASE_F);  // [12544][6272] sh (19,668,992 f)
    unsigned short* ww1bp  = (unsigned short*)(ws + 59006976);   // [6400][1024] sh (3,276,800 f)
    const size_t NEED_BIG = 59006976ull + 3276800ull;            // 62,283,776 f

    // ---- zero padded buffers (ring + tails)
    hipMemsetAsync(full0p, 0, (size_t)37956 * 16 * 2, stream);
    hipMemsetAsync(actPA, 0, (size_t)37956 * 104 * 2, stream);
    hipMemsetAsync(actPB, 0, (size_t)37956 * 104 * 2, stream);
    hipMemsetAsync(gPA, 0, (size_t)2688 * 1024 * 2, stream);
    hipMemsetAsync(gPB, 0, (size_t)2688 * 1024 * 2, stream);

    const size_t haveF = ws_size / 4;
    const bool big = (haveF >= NEED_BIG) && (haveF >= WS_BASE_F + 39337984ull);

    // ---- weight conversions
    k_wcvt<10, 32, 9><<<128, 256, 0, stream>>>(fw0, fw0c, 100, 288);
    for (int i = 0; i < 13; ++i)
        k_wcvt<100, 128, 9><<<128, 256, 0, stream>>>(fw_rest + (size_t)i * 90000,
                                                     fwrb + (size_t)i * 147456, 100, 1152);
    k_wcvt<100, 100, 16><<<1024, 256, 0, stream>>>(ww0, ww0b, 1024, 1600);
    if (big)
        k_wcvt<1024, 1024, 1><<<6400, 256, 0, stream>>>(ww1, ww1bp, 6272, 1024);
    else
        k_wcvt<1024, 1024, 1><<<6272, 256, 0, stream>>>(ww1, ww1b, 6272, 1024);

    // ---- feature network: 14 conv3x3 via implicit-im2col cgemm (padded 194x194)
    k_build_full<<<1440, 256, 0, stream>>>(input, full0p);
    k_cgemm<32, 16, 194, 1><<<dim3(295, 1), 256, 0, stream>>>(fw0c, full0p, fb0, actPA, 100, 104);
    unsigned short* src = actPA;
    unsigned short* dst = actPB;
    for (int i = 0; i < 13; ++i) {
        k_cgemm<128, 104, 194, 1><<<dim3(295, 1), 256, 0, stream>>>(
            fwrb + (size_t)i * 147456, src, fb_rest + i * 100, dst, 100, 104);
        unsigned short* t = src; src = dst; dst = t;
    }
    // src == final feature map (padded)

    // ---- weight network head: conv4x4 s4 -> padded 50x50 [1024]
    k_im2col4<<<2304, 256, 0, stream>>>(src, col4);
    k_gemm<0, 0, 3, 0><<<dim3(18, 8), 256, 0, stream>>>(ww0b, col4, wb0, gPA, 1600, 1024, 1024);

    // ---- 3 x conv3x3 1024->1024 at 48x48 via cgemm on padded 50x50
    k_wcvt<1024, 1024, 9><<<1024, 256, 0, stream>>>(ww_mid, wmb, 1024, 9216);
    k_cgemm<1024, 1024, 50, 2><<<dim3(20, 8), 256, 0, stream>>>(wmb, gPA, wb_mid, gPB, 1024, 1024);
    k_wcvt<1024, 1024, 9><<<1024, 256, 0, stream>>>(ww_mid + (size_t)9437184, wmb, 1024, 9216);
    k_cgemm<1024, 1024, 50, 2><<<dim3(20, 8), 256, 0, stream>>>(wmb, gPB, wb_mid + 1024, gPA, 1024, 1024);
    k_wcvt<1024, 1024, 9><<<1024, 256, 0, stream>>>(ww_mid + (size_t)2 * 9437184, wmb, 1024, 9216);
    k_cgemm<1024, 1024, 50, 4><<<dim3(20, 8), 256, 0, stream>>>(wmb, gPA, wb_mid + 2048, gcmp, 1024, 1024);

    // ---- two 1x1 convs (GEMMs)
    if (big) {
        // 256^2 deep-pipelined path: ww1 (M padded 6272->6400), then ww2
        k_gemm256<0, 0, 1><<<dim3(9, 25), 512, 0, stream>>>(ww1bp, gcmp, wb1, g1, 1024, 6272, 6272);
        k_cvt_flat<<<76832, 256, 0, stream>>>(ww2, ww2b, (size_t)12544 * 6272);
        k_gemm256<1, 1, 1><<<dim3(9, 49), 512, 0, stream>>>(ww2b, g1, wb2, WmT, 6272, 12544, 12544);
    } else {
        k_gemm<0, 0, 0, 1><<<dim3(18, 49), 256, 0, stream>>>(ww1b, gcmp, wb1, g1, 1024, 6272, 6272);
        k_gemm_f32a<1, 1, 1><<<dim3(18, 98), 256, 0, stream>>>(ww2, g1, wb2, WmT, 6272, 12544, 12544);
    }

    // ---- per-pixel solve
    k_solve<<<2304, 256, 0, stream>>>(WmT, design, input, out);
}

// Round 4
// 2324.500 us; speedup vs baseline: 1.4562x; 1.0161x over previous
//
#include <hip/hip_runtime.h>
#include <math.h>

#define LRELU(v) ((v) > 0.f ? (v) : 0.01f * (v))

typedef __attribute__((ext_vector_type(8))) short bf8v;   // 8 x bf16 (4 VGPRs)
typedef __attribute__((ext_vector_type(4))) float f4v;    // MFMA accumulator

// fp32 -> bf16 round-to-nearest-even
static __device__ __forceinline__ unsigned short f2b(float f) {
    unsigned int u = __float_as_uint(f);
    unsigned int r = (u + 0x7fffu + ((u >> 16) & 1u)) >> 16;
    return (unsigned short)r;
}

// async global->LDS, 16B per lane; LDS dest must be linear (base + tid*16).
static __device__ __forceinline__ void gload16(const unsigned short* g, unsigned short* l) {
    __builtin_amdgcn_global_load_lds(
        (__attribute__((address_space(1))) void*)(g),
        (__attribute__((address_space(3))) void*)(l), 16, 0, 0);
}

// ---------------------------------------------------------------------------
// K1: build zero-ring-padded full-res image, pixel-major bf16 [194*194][16]
// ---------------------------------------------------------------------------
__global__ __launch_bounds__(256) void k_build_full(const float* __restrict__ in,
                                                    unsigned short* __restrict__ full0p) {
    int idx = blockIdx.x * 256 + threadIdx.x;
    if (idx >= 368640) return;
    int c = idx % 10, pix = idx / 10;
    int X = pix % 192, Y = pix / 192;
    int t = (Y & 3) * 4 + (X & 3);
    int h = Y >> 2, w = X >> 2;
    int pp = (Y + 1) * 194 + (X + 1);
    full0p[(size_t)pp * 16 + c] = f2b(in[(((t * 10 + c) * 48) + h) * 48 + w]);
}

// ---------------------------------------------------------------------------
// K2: weight convert+permute fp32 -> bf16.
// ---------------------------------------------------------------------------
template <int C, int CP, int Q>
__global__ __launch_bounds__(256) void k_wcvt(const float* __restrict__ src,
                                              unsigned short* __restrict__ dst,
                                              int Mv, int Kp) {
    int m = blockIdx.x;
    for (int kp = threadIdx.x; kp < Kp; kp += 256) {
        int qq = kp / CP, c = kp - qq * CP;
        float v = 0.f;
        if (m < Mv && c < C && qq < Q)
            v = src[((size_t)m * C + c) * Q + qq];
        dst[(size_t)m * Kp + kp] = f2b(v);
    }
}

// K2b: flat fp32 -> bf16 convert
__global__ __launch_bounds__(256) void k_cvt_flat(const float* __restrict__ src,
                                                  unsigned short* __restrict__ dst,
                                                  size_t n) {
    size_t i = ((size_t)blockIdx.x * 256 + threadIdx.x) * 4;
    if (i >= n) return;
    float4 v = *(const float4*)(src + i);
    ushort4 o;
    o.x = f2b(v.x); o.y = f2b(v.y); o.z = f2b(v.z); o.w = f2b(v.w);
    *(ushort4*)(dst + i) = o;
}

// ---------------------------------------------------------------------------
// K4: im2col 4x4 stride4 from PADDED feature map [194*194][104]
// ---------------------------------------------------------------------------
__global__ __launch_bounds__(256) void k_im2col4(const unsigned short* __restrict__ src,
                                                 unsigned short* __restrict__ dst) {
    int p = blockIdx.x;  // 0..2303
    int x = p % 48, y = p / 48;
    for (int kp = threadIdx.x; kp < 1600; kp += 256) {
        int qq = kp / 100, c = kp - qq * 100;
        int yy = y * 4 + (qq >> 2), xx = x * 4 + (qq & 3);
        dst[(size_t)p * 1600 + kp] = src[(size_t)((yy + 1) * 194 + (xx + 1)) * 104 + c];
    }
}

// ---------------------------------------------------------------------------
// K5: MFMA GEMM (m97 2-phase structure) — head gemm + fallbacks.
// ---------------------------------------------------------------------------
template <int ACT, int OF32, int REMAP, int SWZ>
__global__ __launch_bounds__(256) void k_gemm(
    const unsigned short* __restrict__ A, const unsigned short* __restrict__ Bt,
    const float* __restrict__ bias, void* __restrict__ outv,
    int K, int Mv, int ldout) {
    __shared__ __align__(16) unsigned short As[128 * 32];
    __shared__ __align__(16) unsigned short Bs[128 * 32];
    const int tid = threadIdx.x;
    const int lane = tid & 63;
    const int w = tid >> 6;
    const int wm = w >> 1, wn = w & 1;
    const int q = lane >> 4, ln = lane & 15;
    int bx = blockIdx.x, by = blockIdx.y;
    if (SWZ) {
        int gx = gridDim.x;
        int nwg = gx * gridDim.y;
        int lin = by * gx + bx;
        int qq = nwg >> 3, rr = nwg & 7;
        int xcd = lin & 7, idx = lin >> 3;
        int wg = (xcd < rr ? xcd * (qq + 1) : rr * (qq + 1) + (xcd - rr) * qq) + idx;
        bx = wg % gx; by = wg / gx;
    }
    const int m0 = by * 128, n0 = bx * 128;

    f4v acc[4][4];
#pragma unroll
    for (int i = 0; i < 4; ++i)
#pragma unroll
        for (int j = 0; j < 4; ++j) acc[i][j] = (f4v){0.f, 0.f, 0.f, 0.f};

    const int br0 = tid >> 2, bk0 = (tid & 3) << 3;
    const unsigned short* pA0 = A + (size_t)(m0 + br0) * K + bk0;
    const unsigned short* pA1 = pA0 + (size_t)64 * K;
    const unsigned short* pB0 = Bt + (size_t)(n0 + br0) * K + bk0;
    const unsigned short* pB1 = pB0 + (size_t)64 * K;
    unsigned short* lA0 = As + tid * 8;
    unsigned short* lA1 = As + 2048 + tid * 8;
    unsigned short* lB0 = Bs + tid * 8;
    unsigned short* lB1 = Bs + 2048 + tid * 8;
    const unsigned short* Ap2 = &As[(wm * 64 + ln) * 32 + q * 8];
    const unsigned short* Bp2 = &Bs[(wn * 64 + ln) * 32 + q * 8];

    for (int k0 = 0; k0 < K; k0 += 32) {
        gload16(pA0 + k0, lA0);
        gload16(pA1 + k0, lA1);
        gload16(pB0 + k0, lB0);
        gload16(pB1 + k0, lB1);
        __syncthreads();
        bf8v af[4], bfv[4];
#pragma unroll
        for (int i = 0; i < 4; ++i) af[i] = *(const bf8v*)(Ap2 + i * 512);
#pragma unroll
        for (int j = 0; j < 4; ++j) bfv[j] = *(const bf8v*)(Bp2 + j * 512);
#pragma unroll
        for (int i = 0; i < 4; ++i)
#pragma unroll
            for (int j = 0; j < 4; ++j)
                acc[i][j] = __builtin_amdgcn_mfma_f32_16x16x32_bf16(af[i], bfv[j], acc[i][j], 0, 0, 0);
        __syncthreads();
    }

    float* tb = ((float*)As) + w * 288;
#pragma unroll
    for (int i = 0; i < 4; ++i) {
        const int mbase = m0 + wm * 64 + i * 16;
        float bi[4];
#pragma unroll
        for (int r = 0; r < 4; ++r) {
            int mm = mbase + q * 4 + r;
            bi[r] = (mm < Mv) ? bias[mm] : 0.f;
        }
#pragma unroll
        for (int j = 0; j < 4; ++j) {
            const int nbase = n0 + wn * 64 + j * 16;
#pragma unroll
            for (int r = 0; r < 4; ++r) {
                float v = acc[i][j][r] + bi[r];
                v = ACT ? tanhf(v) : LRELU(v);
                tb[ln * 17 + q * 4 + r] = v;
            }
#pragma unroll
            for (int r = 0; r < 4; ++r) {
                float v = tb[(q * 4 + r) * 17 + ln];
                int n = nbase + q * 4 + r;
                int m = mbase + ln;
                if (m < Mv) {
                    if (REMAP == 3) {
                        int y = n / 48, x = n - y * 48;
                        size_t np = (size_t)((y + 1) * 50 + x + 1);
                        ((unsigned short*)outv)[np * (size_t)ldout + m] = f2b(v);
                    } else {
                        if (OF32) ((float*)outv)[(size_t)n * ldout + m] = v;
                        else ((unsigned short*)outv)[(size_t)n * ldout + m] = f2b(v);
                    }
                }
            }
        }
    }
}

// ---------------------------------------------------------------------------
// K5big v2: 256x256 deep-pipelined GEMM with ks-half software pipelining.
// Per tile t: [ds ks0(t)] [MFMA ks1(t-1): regs] [ds ks1(t)] [MFMA ks0(t)]
// [lgkm0; bar] [stage t+2 -> buf cur; vmcnt(8)] [bar].
// Same sync invariants and accumulation order as round-3 verified kernel;
// both read batches now overlap register-only MFMA clusters.
// ---------------------------------------------------------------------------
template <int ACT, int OF32, int SWZ>
__global__ __launch_bounds__(512, 1) void k_gemm256(
    const unsigned short* __restrict__ A, const unsigned short* __restrict__ Bt,
    const float* __restrict__ bias, void* __restrict__ outv,
    int K, int Mv, int ldout) {
    __shared__ __align__(16) unsigned short As[2][16384];
    __shared__ __align__(16) unsigned short Bs[2][16384];
    const int tid = threadIdx.x;          // 0..511
    const int lane = tid & 63;
    const int w = tid >> 6;               // 0..7
    const int wm = w >> 2;                // 0..1
    const int wn = w & 3;                 // 0..3
    const int q = lane >> 4, ln = lane & 15;

    int bx = blockIdx.x, by = blockIdx.y;
    if (SWZ) {
        int gx = gridDim.x;
        int nwg = gx * gridDim.y;
        int lin = by * gx + bx;
        int qq = nwg >> 3, rr = nwg & 7;
        int xcd = lin & 7, idx = lin >> 3;
        int wg = (xcd < rr ? xcd * (qq + 1) : rr * (qq + 1) + (xcd - rr) * qq) + idx;
        bx = wg % gx; by = wg / gx;
    }
    const int m0 = by * 256, n0 = bx * 256;

    f4v acc[8][4];
#pragma unroll
    for (int i = 0; i < 8; ++i)
#pragma unroll
        for (int j = 0; j < 4; ++j) acc[i][j] = (f4v){0.f, 0.f, 0.f, 0.f};

    // staging: chunk c = r*512+tid -> row r*64 + (tid>>3), 16B-chunk tid&7
    const int srow = tid >> 3;            // 0..63
    const int sj = tid & 7;
    const int sjx = sj ^ (srow & 7);      // pre-swizzled source chunk (involution)
    const unsigned short* gA = A + (size_t)(m0 + srow) * K + sjx * 8;
    const unsigned short* gB = Bt + (size_t)(n0 + srow) * K + sjx * 8;
    const size_t rstride = (size_t)64 * K;
    unsigned short* lA = &As[0][0] + tid * 8;
    unsigned short* lB = &Bs[0][0] + tid * 8;

#define STAGE256(buf, t)                                               \
    {                                                                  \
        const unsigned short* ga_ = gA + (size_t)(t) * 64;             \
        const unsigned short* gb_ = gB + (size_t)(t) * 64;             \
        unsigned short* la_ = lA + (buf) * 16384;                      \
        unsigned short* lb_ = lB + (buf) * 16384;                      \
        _Pragma("unroll")                                              \
        for (int r_ = 0; r_ < 4; ++r_) {                               \
            gload16(ga_ + r_ * rstride, la_ + r_ * 4096);              \
            gload16(gb_ + r_ * rstride, lb_ + r_ * 4096);              \
        }                                                              \
    }

    // read offsets (elts).  row&7 == ln&7 for all fragment rows.
    int aoff[8], boff[4];
#pragma unroll
    for (int mf = 0; mf < 8; ++mf) aoff[mf] = (wm * 128 + mf * 16 + ln) * 64;
#pragma unroll
    for (int nf = 0; nf < 4; ++nf) boff[nf] = (wn * 64 + nf * 16 + ln) * 64;
    const int l7 = ln & 7;
    const int koff0 = ((0 * 4 + q) ^ l7) * 8;   // ks=0
    const int koff1 = ((1 * 4 + q) ^ l7) * 8;   // ks=1

    const int NT = K >> 6;
    STAGE256(0, 0);
    STAGE256(1, 1);
    asm volatile("s_waitcnt vmcnt(8)" ::: "memory");
    __builtin_amdgcn_sched_barrier(0);
    __builtin_amdgcn_s_barrier();

    bf8v a0[8], b0[4], a1[8], b1[4];

    // ---- tile 0 (peel: no prev-ks1 MFMA)
    {
        const unsigned short* as = &As[0][0];
        const unsigned short* bs = &Bs[0][0];
#pragma unroll
        for (int mf = 0; mf < 8; ++mf) a0[mf] = *(const bf8v*)&as[aoff[mf] + koff0];
#pragma unroll
        for (int nf = 0; nf < 4; ++nf) b0[nf] = *(const bf8v*)&bs[boff[nf] + koff0];
#pragma unroll
        for (int mf = 0; mf < 8; ++mf) a1[mf] = *(const bf8v*)&as[aoff[mf] + koff1];
#pragma unroll
        for (int nf = 0; nf < 4; ++nf) b1[nf] = *(const bf8v*)&bs[boff[nf] + koff1];
        __builtin_amdgcn_s_setprio(1);
#pragma unroll
        for (int mf = 0; mf < 8; ++mf)
#pragma unroll
            for (int nf = 0; nf < 4; ++nf)
                acc[mf][nf] = __builtin_amdgcn_mfma_f32_16x16x32_bf16(a0[mf], b0[nf], acc[mf][nf], 0, 0, 0);
        __builtin_amdgcn_s_setprio(0);
        asm volatile("s_waitcnt lgkmcnt(0)" ::: "memory");
        __builtin_amdgcn_sched_barrier(0);
        __builtin_amdgcn_s_barrier();
        if (2 < NT) {
            STAGE256(0, 2);
            asm volatile("s_waitcnt vmcnt(8)" ::: "memory");
        } else {
            asm volatile("s_waitcnt vmcnt(0)" ::: "memory");
        }
        __builtin_amdgcn_sched_barrier(0);
        __builtin_amdgcn_s_barrier();
    }

    for (int t = 1; t < NT; ++t) {
        const int cur = t & 1;
        const unsigned short* as = &As[cur][0];
        const unsigned short* bs = &Bs[cur][0];
        // issue ks0 reads of tile t
#pragma unroll
        for (int mf = 0; mf < 8; ++mf) a0[mf] = *(const bf8v*)&as[aoff[mf] + koff0];
#pragma unroll
        for (int nf = 0; nf < 4; ++nf) b0[nf] = *(const bf8v*)&bs[boff[nf] + koff0];
        // MFMA ks1 of tile t-1 (register-only, overlaps reads)
        __builtin_amdgcn_s_setprio(1);
#pragma unroll
        for (int mf = 0; mf < 8; ++mf)
#pragma unroll
            for (int nf = 0; nf < 4; ++nf)
                acc[mf][nf] = __builtin_amdgcn_mfma_f32_16x16x32_bf16(a1[mf], b1[nf], acc[mf][nf], 0, 0, 0);
        __builtin_amdgcn_s_setprio(0);
        // issue ks1 reads of tile t
#pragma unroll
        for (int mf = 0; mf < 8; ++mf) a1[mf] = *(const bf8v*)&as[aoff[mf] + koff1];
#pragma unroll
        for (int nf = 0; nf < 4; ++nf) b1[nf] = *(const bf8v*)&bs[boff[nf] + koff1];
        // MFMA ks0 of tile t (waits only on ks0 reads; ks1 stay in flight)
        __builtin_amdgcn_s_setprio(1);
#pragma unroll
        for (int mf = 0; mf < 8; ++mf)
#pragma unroll
            for (int nf = 0; nf < 4; ++nf)
                acc[mf][nf] = __builtin_amdgcn_mfma_f32_16x16x32_bf16(a0[mf], b0[nf], acc[mf][nf], 0, 0, 0);
        __builtin_amdgcn_s_setprio(0);
        // all reads of buf[cur] drained before staging overwrites it
        asm volatile("s_waitcnt lgkmcnt(0)" ::: "memory");
        __builtin_amdgcn_sched_barrier(0);
        __builtin_amdgcn_s_barrier();
        if (t + 2 < NT) {
            STAGE256(cur, t + 2);
            asm volatile("s_waitcnt vmcnt(8)" ::: "memory");  // tile t+1 landed
        } else {
            asm volatile("s_waitcnt vmcnt(0)" ::: "memory");
        }
        __builtin_amdgcn_sched_barrier(0);
        __builtin_amdgcn_s_barrier();
    }
    // final deferred ks1 of tile NT-1
    __builtin_amdgcn_s_setprio(1);
#pragma unroll
    for (int mf = 0; mf < 8; ++mf)
#pragma unroll
        for (int nf = 0; nf < 4; ++nf)
            acc[mf][nf] = __builtin_amdgcn_mfma_f32_16x16x32_bf16(a1[mf], b1[nf], acc[mf][nf], 0, 0, 0);
    __builtin_amdgcn_s_setprio(0);
    __builtin_amdgcn_s_barrier();
#undef STAGE256

    // transposed epilogue, per-wave 16x17 tile (intra-wave only)
    float* tb = ((float*)&As[0][0]) + w * 288;
#pragma unroll
    for (int mf = 0; mf < 8; ++mf) {
        const int mbase = m0 + wm * 128 + mf * 16;
        float bi[4];
#pragma unroll
        for (int r = 0; r < 4; ++r) {
            int mm = mbase + q * 4 + r;
            bi[r] = (mm < Mv) ? bias[mm] : 0.f;
        }
#pragma unroll
        for (int nf = 0; nf < 4; ++nf) {
            const int nbase = n0 + wn * 64 + nf * 16;
#pragma unroll
            for (int r = 0; r < 4; ++r) {
                float v = acc[mf][nf][r] + bi[r];
                v = ACT ? tanhf(v) : LRELU(v);
                tb[ln * 17 + q * 4 + r] = v;
            }
#pragma unroll
            for (int r = 0; r < 4; ++r) {
                float v = tb[(q * 4 + r) * 17 + ln];
                int n = nbase + q * 4 + r;
                int m = mbase + ln;
                if (m < Mv) {
                    if (OF32) ((float*)outv)[(size_t)n * ldout + m] = v;
                    else ((unsigned short*)outv)[(size_t)n * ldout + m] = f2b(v);
                }
            }
        }
    }
}

// ---------------------------------------------------------------------------
// K5c: conv3x3-as-GEMM with implicit im2col (128-row M tile; verified).
// ---------------------------------------------------------------------------
template <int TAPK, int CST, int SH, int REMAP>
__global__ __launch_bounds__(256) void k_cgemm(
    const unsigned short* __restrict__ A, const unsigned short* __restrict__ Bt,
    const float* __restrict__ bias, unsigned short* __restrict__ outp,
    int Mv, int ldout) {
    __shared__ __align__(16) unsigned short As[128 * 32];
    __shared__ __align__(16) unsigned short Bs[128 * 32];
    const int tid = threadIdx.x;
    const int lane = tid & 63;
    const int w = tid >> 6;
    const int wm = w >> 1, wn = w & 1;
    const int q = lane >> 4, ln = lane & 15;
    const int m0 = blockIdx.y * 128, n0 = blockIdx.x * 128;
    const int KA = 9 * TAPK;

    f4v acc[4][4];
#pragma unroll
    for (int i = 0; i < 4; ++i)
#pragma unroll
        for (int j = 0; j < 4; ++j) acc[i][j] = (f4v){0.f, 0.f, 0.f, 0.f};

    const int br0 = tid >> 2, bk0 = (tid & 3) << 3;
    const unsigned short* pA0 = A + (size_t)(m0 + br0) * KA + bk0;
    const unsigned short* pA1 = pA0 + (size_t)64 * KA;
    unsigned short* lA0 = As + tid * 8;
    unsigned short* lA1 = As + 2048 + tid * 8;
    unsigned short* lB0 = Bs + tid * 8;
    unsigned short* lB1 = Bs + 2048 + tid * 8;
    const unsigned short* Ap2 = &As[(wm * 64 + ln) * 32 + q * 8];
    const unsigned short* Bp2 = &Bs[(wn * 64 + ln) * 32 + q * 8];

#pragma unroll
    for (int tap = 0; tap < 9; ++tap) {
        const int sh = (tap / 3 - 1) * SH + (tap % 3 - 1);
        const unsigned short* pB0 = Bt + (long)(n0 + br0 + sh) * CST + bk0;
        const unsigned short* pB1 = pB0 + (long)64 * CST;
        const int kab = tap * TAPK;
        for (int kk = 0; kk < TAPK; kk += 32) {
            gload16(pA0 + kab + kk, lA0);
            gload16(pA1 + kab + kk, lA1);
            gload16(pB0 + kk, lB0);
            gload16(pB1 + kk, lB1);
            __syncthreads();
            bf8v af[4], bfv[4];
#pragma unroll
            for (int i = 0; i < 4; ++i) af[i] = *(const bf8v*)(Ap2 + i * 512);
#pragma unroll
            for (int j = 0; j < 4; ++j) bfv[j] = *(const bf8v*)(Bp2 + j * 512);
#pragma unroll
            for (int i = 0; i < 4; ++i)
#pragma unroll
                for (int j = 0; j < 4; ++j)
                    acc[i][j] = __builtin_amdgcn_mfma_f32_16x16x32_bf16(af[i], bfv[j], acc[i][j], 0, 0, 0);
            __syncthreads();
        }
    }

    float* tb = ((float*)As) + w * 288;
#pragma unroll
    for (int i = 0; i < 4; ++i) {
        const int mbase = m0 + wm * 64 + i * 16;
        float bi[4];
#pragma unroll
        for (int r = 0; r < 4; ++r) {
            int mm = mbase + q * 4 + r;
            bi[r] = (mm < Mv) ? bias[mm] : 0.f;
        }
#pragma unroll
        for (int j = 0; j < 4; ++j) {
            const int nbase = n0 + wn * 64 + j * 16;
#pragma unroll
            for (int r = 0; r < 4; ++r) {
                float v = acc[i][j][r] + bi[r];
                v = LRELU(v);
                tb[ln * 17 + q * 4 + r] = v;
            }
#pragma unroll
            for (int r = 0; r < 4; ++r) {
                float v = tb[(q * 4 + r) * 17 + ln];
                int n = nbase + q * 4 + r;
                int m = mbase + ln;
                if (m < Mv) {
                    if (REMAP == 1) {
                        int y = n / 194, x = n - y * 194;
                        bool z = (n >= 37636) || y == 0 || y >= 193 || x == 0 || x >= 193;
                        outp[(size_t)n * ldout + m] = f2b(z ? 0.f : v);
                    } else if (REMAP == 2) {
                        int y = n / 50, x = n - y * 50;
                        bool z = (n >= 2500) || y == 0 || y >= 49 || x == 0 || x >= 49;
                        outp[(size_t)n * ldout + m] = f2b(z ? 0.f : v);
                    } else if (REMAP == 4) {
                        int y = n / 50, x = n - y * 50;
                        if (n < 2500 && y >= 1 && y <= 48 && x >= 1 && x <= 48)
                            outp[(size_t)((y - 1) * 48 + (x - 1)) * ldout + m] = f2b(v);
                    }
                }
            }
        }
    }
}

// ---------------------------------------------------------------------------
// K5c64: conv3x3 cgemm with 64-row M tile (4 waves as 1M x 4N, wave 64x32).
// Doubles grid blocks for the mid convs (160 -> 320, all CUs busy).
// Same tap/k accumulation order as k_cgemm -> identical numerics.
// ---------------------------------------------------------------------------
template <int TAPK, int CST, int SH, int REMAP>
__global__ __launch_bounds__(256) void k_cgemm64(
    const unsigned short* __restrict__ A, const unsigned short* __restrict__ Bt,
    const float* __restrict__ bias, unsigned short* __restrict__ outp,
    int Mv, int ldout) {
    __shared__ __align__(16) unsigned short As[64 * 32];
    __shared__ __align__(16) unsigned short Bs[128 * 32];
    const int tid = threadIdx.x;
    const int lane = tid & 63;
    const int wn = tid >> 6;  // 0..3
    const int q = lane >> 4, ln = lane & 15;
    const int m0 = blockIdx.y * 64, n0 = blockIdx.x * 128;
    const int KA = 9 * TAPK;

    f4v acc[4][2];
#pragma unroll
    for (int i = 0; i < 4; ++i)
#pragma unroll
        for (int j = 0; j < 2; ++j) acc[i][j] = (f4v){0.f, 0.f, 0.f, 0.f};

    const int br0 = tid >> 2, bk0 = (tid & 3) << 3;  // br0 0..63
    const unsigned short* pA0 = A + (size_t)(m0 + br0) * KA + bk0;
    unsigned short* lA0 = As + tid * 8;   // 256 chunks = 4 KB (rows 0..63)
    unsigned short* lB0 = Bs + tid * 8;
    unsigned short* lB1 = Bs + 2048 + tid * 8;
    const unsigned short* Ap2 = &As[ln * 32 + q * 8];
    const unsigned short* Bp2 = &Bs[(wn * 32 + ln) * 32 + q * 8];

#pragma unroll
    for (int tap = 0; tap < 9; ++tap) {
        const int sh = (tap / 3 - 1) * SH + (tap % 3 - 1);
        const unsigned short* pB0 = Bt + (long)(n0 + br0 + sh) * CST + bk0;
        const unsigned short* pB1 = pB0 + (long)64 * CST;
        const int kab = tap * TAPK;
        for (int kk = 0; kk < TAPK; kk += 32) {
            gload16(pA0 + kab + kk, lA0);
            gload16(pB0 + kk, lB0);
            gload16(pB1 + kk, lB1);
            __syncthreads();
            bf8v af[4], bfv[2];
#pragma unroll
            for (int i = 0; i < 4; ++i) af[i] = *(const bf8v*)(Ap2 + i * 512);
#pragma unroll
            for (int j = 0; j < 2; ++j) bfv[j] = *(const bf8v*)(Bp2 + j * 512);
#pragma unroll
            for (int i = 0; i < 4; ++i)
#pragma unroll
                for (int j = 0; j < 2; ++j)
                    acc[i][j] = __builtin_amdgcn_mfma_f32_16x16x32_bf16(af[i], bfv[j], acc[i][j], 0, 0, 0);
            __syncthreads();
        }
    }

    float* tb = ((float*)Bs) + wn * 288;  // 4 x 288 floats fits in Bs (8 KB)
#pragma unroll
    for (int i = 0; i < 4; ++i) {
        const int mbase = m0 + i * 16;
        float bi[4];
#pragma unroll
        for (int r = 0; r < 4; ++r) {
            int mm = mbase + q * 4 + r;
            bi[r] = (mm < Mv) ? bias[mm] : 0.f;
        }
#pragma unroll
        for (int j = 0; j < 2; ++j) {
            const int nbase = n0 + wn * 32 + j * 16;
#pragma unroll
            for (int r = 0; r < 4; ++r) {
                float v = acc[i][j][r] + bi[r];
                v = LRELU(v);
                tb[ln * 17 + q * 4 + r] = v;
            }
#pragma unroll
            for (int r = 0; r < 4; ++r) {
                float v = tb[(q * 4 + r) * 17 + ln];
                int n = nbase + q * 4 + r;
                int m = mbase + ln;
                if (m < Mv) {
                    if (REMAP == 2) {
                        int y = n / 50, x = n - y * 50;
                        bool z = (n >= 2500) || y == 0 || y >= 49 || x == 0 || x >= 49;
                        outp[(size_t)n * ldout + m] = f2b(z ? 0.f : v);
                    } else if (REMAP == 4) {
                        int y = n / 50, x = n - y * 50;
                        if (n < 2500 && y >= 1 && y <= 48 && x >= 1 && x <= 48)
                            outp[(size_t)((y - 1) * 48 + (x - 1)) * ldout + m] = f2b(v);
                    }
                }
            }
        }
    }
}

// ---------------------------------------------------------------------------
// K5b: legacy reg-staged GEMM with in-loop fp32->bf16 A conversion (fallback)
// ---------------------------------------------------------------------------
template <int ACT, int OF32, int AF32>
__global__ __launch_bounds__(256) void k_gemm_f32a(
    const void* __restrict__ Ain, const unsigned short* __restrict__ Bt,
    const float* __restrict__ bias, void* __restrict__ outv,
    int K, int Mv, int ldout) {
    __shared__ __align__(16) unsigned short As[128 * 40];
    __shared__ __align__(16) unsigned short Bs[128 * 40];
    const int tid = threadIdx.x;
    const int lane = tid & 63;
    const int w = tid >> 6;
    const int wm = w >> 1, wn = w & 1;
    const int q = lane >> 4, ln = lane & 15;
    const int m0 = blockIdx.y * 128, n0 = blockIdx.x * 128;

    f4v acc[4][4];
#pragma unroll
    for (int i = 0; i < 4; ++i)
#pragma unroll
        for (int j = 0; j < 4; ++j) acc[i][j] = (f4v){0.f, 0.f, 0.f, 0.f};

    const int br0 = tid >> 2, bk0 = (tid & 3) << 3;
    const int br1 = br0 + 64;
    const int bl0 = br0 * 40 + bk0, bl1 = br1 * 40 + bk0;
    const unsigned short* pB0 = Bt + (size_t)(n0 + br0) * K + bk0;
    const unsigned short* pB1 = Bt + (size_t)(n0 + br1) * K + bk0;

    const unsigned short* Ab = (const unsigned short*)Ain;
    const float* Af = (const float*)Ain;
    const unsigned short* pA0 = Ab + (size_t)(m0 + br0) * K + bk0;
    const unsigned short* pA1 = Ab + (size_t)(m0 + br1) * K + bk0;
    const int fr = tid >> 3, fk = (tid & 7) << 2;
    const float* pF = Af + (size_t)(m0 + fr) * K + fk;

    for (int k0 = 0; k0 < K; k0 += 32) {
        if (AF32) {
#pragma unroll
            for (int jj = 0; jj < 4; ++jj) {
                float4 v = *(const float4*)(pF + (size_t)jj * 32 * K + k0);
                unsigned int lo = ((unsigned)f2b(v.y) << 16) | f2b(v.x);
                unsigned int hi = ((unsigned)f2b(v.w) << 16) | f2b(v.z);
                *(uint2*)&As[(fr + jj * 32) * 40 + fk] = make_uint2(lo, hi);
            }
        } else {
            uint4 a0 = *(const uint4*)(pA0 + k0);
            uint4 a1 = *(const uint4*)(pA1 + k0);
            *(uint4*)&As[bl0] = a0;
            *(uint4*)&As[bl1] = a1;
        }
        uint4 b0 = *(const uint4*)(pB0 + k0);
        uint4 b1 = *(const uint4*)(pB1 + k0);
        *(uint4*)&Bs[bl0] = b0;
        *(uint4*)&Bs[bl1] = b1;
        __syncthreads();
        const unsigned short* Ap2 = &As[(wm * 64 + ln) * 40 + q * 8];
        const unsigned short* Bp2 = &Bs[(wn * 64 + ln) * 40 + q * 8];
        bf8v af[4], bfv[4];
#pragma unroll
        for (int i = 0; i < 4; ++i) af[i] = *(const bf8v*)(Ap2 + i * 640);
#pragma unroll
        for (int j = 0; j < 4; ++j) bfv[j] = *(const bf8v*)(Bp2 + j * 640);
#pragma unroll
        for (int i = 0; i < 4; ++i)
#pragma unroll
            for (int j = 0; j < 4; ++j)
                acc[i][j] = __builtin_amdgcn_mfma_f32_16x16x32_bf16(af[i], bfv[j], acc[i][j], 0, 0, 0);
        __syncthreads();
    }

    float* tb = ((float*)As) + w * 288;
#pragma unroll
    for (int i = 0; i < 4; ++i) {
        const int mbase = m0 + wm * 64 + i * 16;
        float bi[4];
#pragma unroll
        for (int r = 0; r < 4; ++r) {
            int mm = mbase + q * 4 + r;
            bi[r] = (mm < Mv) ? bias[mm] : 0.f;
        }
#pragma unroll
        for (int j = 0; j < 4; ++j) {
            const int nbase = n0 + wn * 64 + j * 16;
#pragma unroll
            for (int r = 0; r < 4; ++r) {
                float v = acc[i][j][r] + bi[r];
                v = ACT ? tanhf(v) : LRELU(v);
                tb[ln * 17 + q * 4 + r] = v;
            }
#pragma unroll
            for (int r = 0; r < 4; ++r) {
                float v = tb[(q * 4 + r) * 17 + ln];
                size_t n = nbase + q * 4 + r;
                int m = mbase + ln;
                if (m < Mv) {
                    if (OF32) ((float*)outv)[n * (size_t)ldout + m] = v;
                    else ((unsigned short*)outv)[n * (size_t)ldout + m] = f2b(v);
                }
            }
        }
    }
}

// ---------------------------------------------------------------------------
// K6: per-pixel normal equations + solve (verified, unchanged)
// ---------------------------------------------------------------------------
__global__ __launch_bounds__(256) void k_solve(const float* __restrict__ WmT,
                                               const float* __restrict__ design,
                                               const float* __restrict__ input,
                                               float* __restrict__ out) {
    const int p = blockIdx.x;  // 0..2303
    const int h = p / 48, wpx = p % 48;
    const int tid = threadIdx.x;
    __shared__ float Msh[16 * 17];
    __shared__ float Gsh[16 * 17];
    __shared__ float Xsh[16 * 8];
    __shared__ float Ysh[16 * 4];
    __shared__ float XTWsh[7 * 17];
    __shared__ float Aacc[49];
    __shared__ float Bacc[21];
    __shared__ float parash[21];

    if (tid < 49) Aacc[tid] = 0.f;
    if (tid >= 64 && tid < 85) Bacc[tid - 64] = 0.f;
    __syncthreads();

    const float* wrow = WmT + (size_t)p * 12544;
    for (int ni = 0; ni < 49; ++ni) {
        {
            int t1 = tid >> 4, t2 = tid & 15;
            Msh[t1 * 17 + t2] = wrow[ni * 256 + tid];
        }
        int sy = h + ni / 7 - 3, sx = wpx + ni % 7 - 3;
        bool inb = (sy >= 0 && sy < 48 && sx >= 0 && sx < 48);
        if (tid < 112) {
            int t = tid / 7, c = tid - t * 7;
            Xsh[t * 8 + c] = inb ? design[(size_t)(t * 7 + c) * 2304 + sy * 48 + sx] : 0.f;
        } else if (tid >= 128 && tid < 176) {
            int l = tid - 128;
            int t = l / 3, r = l - t * 3;
            Ysh[t * 4 + r] = inb ? input[(size_t)(t * 10 + r) * 2304 + sy * 48 + sx] : 0.f;
        }
        __syncthreads();
        {
            int t1 = tid >> 4, t2 = tid & 15;
            float s = (t1 == t2) ? 1.f : 0.f;
#pragma unroll
            for (int k = 0; k < 16; ++k) s += Msh[t1 * 17 + k] * Msh[t2 * 17 + k];
            Gsh[t1 * 17 + t2] = s;
        }
        __syncthreads();
        if (tid < 112) {
            int c = tid >> 4, t2 = tid & 15;
            float s = 0.f;
#pragma unroll
            for (int t1 = 0; t1 < 16; ++t1) s += Xsh[t1 * 8 + c] * Gsh[t1 * 17 + t2];
            XTWsh[c * 17 + t2] = s;
        }
        __syncthreads();
        if (tid < 49) {
            int c1 = tid / 7, c2 = tid - c1 * 7;
            float s = 0.f;
#pragma unroll
            for (int t = 0; t < 16; ++t) s += XTWsh[c1 * 17 + t] * Xsh[t * 8 + c2];
            Aacc[tid] += s;
        } else if (tid >= 64 && tid < 85) {
            int l = tid - 64;
            int c = l / 3, r = l - c * 3;
            float s = 0.f;
#pragma unroll
            for (int t = 0; t < 16; ++t) s += XTWsh[c * 17 + t] * Ysh[t * 4 + r];
            Bacc[l] += s;
        }
        __syncthreads();
    }

    if (tid == 0) {
        float Mg[7][10];
#pragma unroll
        for (int i = 0; i < 7; ++i) {
#pragma unroll
            for (int j = 0; j < 7; ++j) Mg[i][j] = Aacc[i * 7 + j] + ((i == j) ? 0.01f : 0.f);
#pragma unroll
            for (int r = 0; r < 3; ++r) Mg[i][7 + r] = Bacc[i * 3 + r];
        }
#pragma unroll
        for (int kk = 0; kk < 7; ++kk) {
            float inv = 1.f / Mg[kk][kk];
#pragma unroll
            for (int j = 0; j < 10; ++j) Mg[kk][j] *= inv;
#pragma unroll
            for (int i = 0; i < 7; ++i) {
                if (i == kk) continue;
                float f = Mg[i][kk];
#pragma unroll
                for (int j = 0; j < 10; ++j) Mg[i][j] -= f * Mg[kk][j];
            }
        }
#pragma unroll
        for (int c = 0; c < 7; ++c)
#pragma unroll
            for (int r = 0; r < 3; ++r) parash[c * 3 + r] = Mg[c][7 + r];
    }
    __syncthreads();

    if (tid < 48) {
        int t = tid / 3, r = tid - t * 3;
        float s = 0.f;
#pragma unroll
        for (int c = 0; c < 7; ++c)
            s += design[(size_t)(t * 7 + c) * 2304 + p] * parash[c * 3 + r];
        out[(size_t)tid * 2304 + p] = s;
    }
}

// ---------------------------------------------------------------------------
extern "C" void kernel_launch(void* const* d_in, const int* in_sizes, int n_in,
                              void* d_out, int out_size, void* d_ws, size_t ws_size,
                              hipStream_t stream) {
    const float* input   = (const float*)d_in[0];
    const float* design  = (const float*)d_in[1];
    const float* fw0     = (const float*)d_in[2];
    const float* fb0     = (const float*)d_in[3];
    const float* fw_rest = (const float*)d_in[4];
    const float* fb_rest = (const float*)d_in[5];
    const float* ww0     = (const float*)d_in[6];
    const float* wb0     = (const float*)d_in[7];
    const float* ww_mid  = (const float*)d_in[8];
    const float* wb_mid  = (const float*)d_in[9];
    const float* ww1     = (const float*)d_in[10];
    const float* wb1     = (const float*)d_in[11];
    const float* ww2     = (const float*)d_in[12];
    const float* wb2     = (const float*)d_in[13];
    float* out = (float*)d_out;
    float* ws = (float*)d_ws;

    // ---- workspace layout (float units).  Region [0, 28,901,376) is scratch
    // during the conv phase and becomes WmT (fp32 [2304][12544]) at ww2 time.
    float* WmT = ws;
    unsigned short* full0p = (unsigned short*)(ws + 40000);      // [37956][16] sh
    unsigned short* actPA  = (unsigned short*)(ws + 350000);     // [37956][104] sh
    unsigned short* actPB  = (unsigned short*)(ws + 2330000);    // [37956][104] sh
    unsigned short* fw0c   = (unsigned short*)(ws + 4310000);    // [128][288] sh
    unsigned short* fwrb   = (unsigned short*)(ws + 4330000);    // 13 x [128][1152] sh
    unsigned short* ww0b   = (unsigned short*)(ws + 5290000);    // [1024][1600] sh
    unsigned short* col4   = (unsigned short*)(ws + 6110000);    // [2304][1600] sh
    unsigned short* gPA    = (unsigned short*)(ws + 7960000);    // [2688][1024] sh
    unsigned short* gPB    = (unsigned short*)(ws + 9340000);    // [2688][1024] sh
    unsigned short* wmb    = (unsigned short*)(ws + 10720000);   // [1024][9216] sh
    unsigned short* gcmp   = (unsigned short*)(ws + 15440000);   // [2304][1024] sh
    unsigned short* g1     = (unsigned short*)(ws + 28901376);   // [2304][6272] sh
    unsigned short* ww1b   = (unsigned short*)(ws + 36126720);   // fallback slot
    const size_t WS_BASE_F = 39337984ull;
    unsigned short* ww2b   = (unsigned short*)(ws + WS_BASE_F);  // [12544][6272] sh (19,668,992 f)
    unsigned short* ww1bp  = (unsigned short*)(ws + 59006976);   // [6400][1024] sh (3,276,800 f)
    const size_t NEED_BIG = 59006976ull + 3276800ull;            // 62,283,776 f

    // ---- zero padded buffers (ring + tails)
    hipMemsetAsync(full0p, 0, (size_t)37956 * 16 * 2, stream);
    hipMemsetAsync(actPA, 0, (size_t)37956 * 104 * 2, stream);
    hipMemsetAsync(actPB, 0, (size_t)37956 * 104 * 2, stream);
    hipMemsetAsync(gPA, 0, (size_t)2688 * 1024 * 2, stream);
    hipMemsetAsync(gPB, 0, (size_t)2688 * 1024 * 2, stream);

    const size_t haveF = ws_size / 4;
    const bool big = (haveF >= NEED_BIG) && (haveF >= WS_BASE_F + 39337984ull);

    // ---- weight conversions
    k_wcvt<10, 32, 9><<<128, 256, 0, stream>>>(fw0, fw0c, 100, 288);
    for (int i = 0; i < 13; ++i)
        k_wcvt<100, 128, 9><<<128, 256, 0, stream>>>(fw_rest + (size_t)i * 90000,
                                                     fwrb + (size_t)i * 147456, 100, 1152);
    k_wcvt<100, 100, 16><<<1024, 256, 0, stream>>>(ww0, ww0b, 1024, 1600);
    if (big)
        k_wcvt<1024, 1024, 1><<<6400, 256, 0, stream>>>(ww1, ww1bp, 6272, 1024);
    else
        k_wcvt<1024, 1024, 1><<<6272, 256, 0, stream>>>(ww1, ww1b, 6272, 1024);

    // ---- feature network: 14 conv3x3 via implicit-im2col cgemm (padded 194x194)
    k_build_full<<<1440, 256, 0, stream>>>(input, full0p);
    k_cgemm<32, 16, 194, 1><<<dim3(295, 1), 256, 0, stream>>>(fw0c, full0p, fb0, actPA, 100, 104);
    unsigned short* src = actPA;
    unsigned short* dst = actPB;
    for (int i = 0; i < 13; ++i) {
        k_cgemm<128, 104, 194, 1><<<dim3(295, 1), 256, 0, stream>>>(
            fwrb + (size_t)i * 147456, src, fb_rest + i * 100, dst, 100, 104);
        unsigned short* t = src; src = dst; dst = t;
    }
    // src == final feature map (padded)

    // ---- weight network head: conv4x4 s4 -> padded 50x50 [1024]
    k_im2col4<<<2304, 256, 0, stream>>>(src, col4);
    k_gemm<0, 0, 3, 0><<<dim3(18, 8), 256, 0, stream>>>(ww0b, col4, wb0, gPA, 1600, 1024, 1024);

    // ---- 3 x conv3x3 1024->1024 at 48x48 via 64-row-tile cgemm (320 blocks)
    k_wcvt<1024, 1024, 9><<<1024, 256, 0, stream>>>(ww_mid, wmb, 1024, 9216);
    k_cgemm64<1024, 1024, 50, 2><<<dim3(20, 16), 256, 0, stream>>>(wmb, gPA, wb_mid, gPB, 1024, 1024);
    k_wcvt<1024, 1024, 9><<<1024, 256, 0, stream>>>(ww_mid + (size_t)9437184, wmb, 1024, 9216);
    k_cgemm64<1024, 1024, 50, 2><<<dim3(20, 16), 256, 0, stream>>>(wmb, gPB, wb_mid + 1024, gPA, 1024, 1024);
    k_wcvt<1024, 1024, 9><<<1024, 256, 0, stream>>>(ww_mid + (size_t)2 * 9437184, wmb, 1024, 9216);
    k_cgemm64<1024, 1024, 50, 4><<<dim3(20, 16), 256, 0, stream>>>(wmb, gPA, wb_mid + 2048, gcmp, 1024, 1024);

    // ---- two 1x1 convs (GEMMs)
    if (big) {
        k_gemm256<0, 0, 1><<<dim3(9, 25), 512, 0, stream>>>(ww1bp, gcmp, wb1, g1, 1024, 6272, 6272);
        k_cvt_flat<<<76832, 256, 0, stream>>>(ww2, ww2b, (size_t)12544 * 6272);
        k_gemm256<1, 1, 1><<<dim3(9, 49), 512, 0, stream>>>(ww2b, g1, wb2, WmT, 6272, 12544, 12544);
    } else {
        k_gemm<0, 0, 0, 1><<<dim3(18, 49), 256, 0, stream>>>(ww1b, gcmp, wb1, g1, 1024, 6272, 6272);
        k_gemm_f32a<1, 1, 1><<<dim3(18, 98), 256, 0, stream>>>(ww2, g1, wb2, WmT, 6272, 12544, 12544);
    }

    // ---- per-pixel solve
    k_solve<<<2304, 256, 0, stream>>>(WmT, design, input, out);
}